// Round 2
// baseline (509.040 us; speedup 1.0000x reference)
//
#include <hip/hip_runtime.h>
#include <hip/hip_bf16.h>
#include <cstdint>
#include <cmath>

#define BDIM 256

constexpr int Bb = 2;
constexpr int Nn = 2048;
constexpr int Cc = 768;
constexpr int Hh = 12;
constexpr int Dd = 64;
constexpr int TC = 3 * Cc;   // 2304
constexpr int BH = Bb * Hh;  // 24
constexpr int NCHUNK = 16;
constexpr int CHROWS = Nn / NCHUNK;  // 128

__device__ __forceinline__ float elu1(float x) {
  return x > 0.f ? x + 1.f : expf(x);
}

// ---------------- generic 64x64-tile fp32 GEMM: C = A[MxK] * B[KxN] (+bias) ----------
template <bool BIAS>
__global__ __launch_bounds__(BDIM) void gemm64(const float* __restrict__ A,
                                               const float* __restrict__ Bm,
                                               const float* __restrict__ bias,
                                               float* __restrict__ Cm,
                                               int M, int K, int Nw) {
  __shared__ float As[16][64];  // [k][m]
  __shared__ float Bs[16][64];  // [k][n]
  const int tid = threadIdx.x;
  const int tx = tid & 15, ty = tid >> 4;
  const int row0 = blockIdx.y * 64, col0 = blockIdx.x * 64;
  const int am = tid >> 2, ak = (tid & 3) << 2;
  const int bk = tid >> 4, bn = (tid & 15) << 2;
  float acc[4][4] = {};
  const float* Ap = A + (size_t)(row0 + am) * K + ak;
  const float* Bp = Bm + (size_t)bk * Nw + col0 + bn;
  for (int k0 = 0; k0 < K; k0 += 16) {
    float4 av = *(const float4*)(Ap + k0);
    float4 bv = *(const float4*)(Bp + (size_t)k0 * Nw);
    __syncthreads();
    As[ak + 0][am] = av.x;
    As[ak + 1][am] = av.y;
    As[ak + 2][am] = av.z;
    As[ak + 3][am] = av.w;
    *(float4*)&Bs[bk][bn] = bv;
    __syncthreads();
#pragma unroll
    for (int kk = 0; kk < 16; ++kk) {
      float4 a4 = *(const float4*)&As[kk][ty << 2];
      float4 b4 = *(const float4*)&Bs[kk][tx << 2];
      const float aa[4] = {a4.x, a4.y, a4.z, a4.w};
      const float bb[4] = {b4.x, b4.y, b4.z, b4.w};
#pragma unroll
      for (int i = 0; i < 4; ++i)
#pragma unroll
        for (int j = 0; j < 4; ++j) acc[i][j] += aa[i] * bb[j];
    }
  }
#pragma unroll
  for (int i = 0; i < 4; ++i) {
    float4 o;
    o.x = acc[i][0];
    o.y = acc[i][1];
    o.z = acc[i][2];
    o.w = acc[i][3];
    if (BIAS) {
      int cb = col0 + (tx << 2);
      o.x += bias[cb + 0];
      o.y += bias[cb + 1];
      o.z += bias[cb + 2];
      o.w += bias[cb + 3];
    }
    *(float4*)&Cm[(size_t)(row0 + (ty << 2) + i) * Nw + col0 + (tx << 2)] = o;
  }
}

// ---------------- qkv -> q' = elu(q)+1, k' = elu(k)+1 in [B,H,N,D] layout ------------
__global__ __launch_bounds__(BDIM) void qk_transform(const float* __restrict__ qkv,
                                                     float* __restrict__ qp,
                                                     float* __restrict__ kp) {
  const int per = BH * Nn * (Dd / 4);  // 786432
  int i = blockIdx.x * BDIM + threadIdx.x;
  int tt = i / per;  // 0 = q, 1 = k
  int r = i - tt * per;
  int d4 = r & 15;
  int t = r >> 4;
  int n = t & (Nn - 1);
  t >>= 11;
  int h = t % Hh;
  int b = t / Hh;
  float4 v = *(const float4*)&qkv[(size_t)(b * Nn + n) * TC + tt * Cc + h * Dd + d4 * 4];
  float4 o;
  o.x = elu1(v.x);
  o.y = elu1(v.y);
  o.z = elu1(v.z);
  o.w = elu1(v.w);
  float* dst = tt ? kp : qp;
  *(float4*)&dst[(size_t)r * 4] = o;
}

// ---------------- partial KV = k'^T v  and  Ksum = sum_n k' --------------------------
__global__ __launch_bounds__(BDIM) void kv_partial(const float* __restrict__ kp,
                                                   const float* __restrict__ qkv,
                                                   float* __restrict__ kvpart,
                                                   float* __restrict__ kspart) {
  const int chunk = blockIdx.x, bh = blockIdx.y;
  const int b = bh / Hh, h = bh % Hh;
  __shared__ float ks[8][64];
  __shared__ float vs[8][64];
  const int tid = threadIdx.x;
  const int nn = tid >> 5, f2 = (tid & 31) << 1;
  const int e = tid & 63, dg = tid >> 6;
  float acc[16] = {};
  float ksacc = 0.f;
  const int n0base = chunk * CHROWS;
  for (int s = 0; s < CHROWS; s += 8) {
    int n = n0base + s + nn;
    float2 k2 = *(const float2*)&kp[(size_t)(bh * Nn + n) * 64 + f2];
    float2 v2 = *(const float2*)&qkv[(size_t)(b * Nn + n) * TC + 2 * Cc + h * Dd + f2];
    __syncthreads();
    *(float2*)&ks[nn][f2] = k2;
    *(float2*)&vs[nn][f2] = v2;
    __syncthreads();
#pragma unroll
    for (int j = 0; j < 8; ++j) {
      float vv = vs[j][e];
#pragma unroll
      for (int d = 0; d < 16; ++d) acc[d] += ks[j][dg * 16 + d] * vv;
      if (tid < 64) ksacc += ks[j][tid];
    }
  }
  float* outp = kvpart + (size_t)(bh * NCHUNK + chunk) * 4096;
#pragma unroll
  for (int d = 0; d < 16; ++d) outp[(dg * 16 + d) * 64 + e] = acc[d];
  if (tid < 64) kspart[(bh * NCHUNK + chunk) * 64 + tid] = ksacc;
}

__global__ __launch_bounds__(BDIM) void kv_reduce(const float* __restrict__ kvpart,
                                                  const float* __restrict__ kspart,
                                                  float* __restrict__ kv,
                                                  float* __restrict__ ksum) {
  const int bh = blockIdx.x, tid = threadIdx.x;
#pragma unroll
  for (int i = 0; i < 16; ++i) {
    int idx = i * 256 + tid;
    float s = 0.f;
    for (int c = 0; c < NCHUNK; ++c) s += kvpart[(size_t)(bh * NCHUNK + c) * 4096 + idx];
    kv[(size_t)bh * 4096 + idx] = s;
  }
  if (tid < 64) {
    float s = 0.f;
    for (int c = 0; c < NCHUNK; ++c) s += kspart[(bh * NCHUNK + c) * 64 + tid];
    ksum[bh * 64 + tid] = s;
  }
}

// ---------------- denom[b,h,n] = q' . Ksum -------------------------------------------
__global__ __launch_bounds__(BDIM) void denom_kernel(const float* __restrict__ qp,
                                                     const float* __restrict__ ksum,
                                                     float* __restrict__ denom) {
  const int bh = blockIdx.y;
  const int n = blockIdx.x * BDIM + threadIdx.x;
  __shared__ float kss[64];
  if (threadIdx.x < 64) kss[threadIdx.x] = ksum[bh * 64 + threadIdx.x];
  __syncthreads();
  const float* qrow = qp + (size_t)(bh * Nn + n) * 64;
  float s = 0.f;
#pragma unroll
  for (int d4 = 0; d4 < 16; ++d4) {
    float4 q = *(const float4*)(qrow + d4 * 4);
    s += q.x * kss[d4 * 4] + q.y * kss[d4 * 4 + 1] + q.z * kss[d4 * 4 + 2] +
         q.w * kss[d4 * 4 + 3];
  }
  denom[bh * Nn + n] = s;
}

// ---------------- attn tile: (Q' K'^T) / denom ---------------------------------------
__global__ __launch_bounds__(BDIM) void attn_kernel(const float* __restrict__ qp,
                                                    const float* __restrict__ kp,
                                                    const float* __restrict__ denom,
                                                    float* __restrict__ attn) {
  const int tj = blockIdx.x, ti = blockIdx.y, bh = blockIdx.z;
  __shared__ float Qs[64][68];  // [d][n], padded
  __shared__ float Ks[64][68];  // [d][m]
  const int tid = threadIdx.x;
  const int tx = tid & 15, ty = tid >> 4;
  const int lr = tid >> 2, ld4 = (tid & 3) << 2;
  const int row0 = ti * 64, col0 = tj * 64;
  const float* qbase = qp + (size_t)(bh * Nn + row0) * 64;
  const float* kbase = kp + (size_t)(bh * Nn + col0) * 64;
#pragma unroll
  for (int it = 0; it < 4; ++it) {
    int dd = ld4 + it * 16;  // walk the d-blocks; row is fixed at lr
    float4 q4 = *(const float4*)(qbase + lr * 64 + dd);
    float4 k4 = *(const float4*)(kbase + lr * 64 + dd);
    Qs[dd + 0][lr] = q4.x;
    Qs[dd + 1][lr] = q4.y;
    Qs[dd + 2][lr] = q4.z;
    Qs[dd + 3][lr] = q4.w;
    Ks[dd + 0][lr] = k4.x;
    Ks[dd + 1][lr] = k4.y;
    Ks[dd + 2][lr] = k4.z;
    Ks[dd + 3][lr] = k4.w;
  }
  __syncthreads();
  float acc[4][4] = {};
#pragma unroll 16
  for (int d = 0; d < 64; ++d) {
    float4 a4 = *(const float4*)&Qs[d][ty << 2];
    float4 b4 = *(const float4*)&Ks[d][tx << 2];
    const float aa[4] = {a4.x, a4.y, a4.z, a4.w};
    const float bb[4] = {b4.x, b4.y, b4.z, b4.w};
#pragma unroll
    for (int i = 0; i < 4; ++i)
#pragma unroll
      for (int j = 0; j < 4; ++j) acc[i][j] += aa[i] * bb[j];
  }
#pragma unroll
  for (int i = 0; i < 4; ++i) {
    int row = row0 + (ty << 2) + i;
    float rd = 1.0f / denom[bh * Nn + row];
    float4 o;
    o.x = acc[i][0] * rd;
    o.y = acc[i][1] * rd;
    o.z = acc[i][2] * rd;
    o.w = acc[i][3] * rd;
    *(float4*)&attn[((size_t)bh * Nn + row) * Nn + col0 + (tx << 2)] = o;
  }
}

// ---------------- out_pre[b,n,h*64+c] = (q' . KV[:,c]) / denom -----------------------
__global__ __launch_bounds__(BDIM) void outpre_kernel(const float* __restrict__ qp,
                                                      const float* __restrict__ kv,
                                                      const float* __restrict__ denom,
                                                      float* __restrict__ outpre) {
  const int nc = blockIdx.x, bh = blockIdx.y;
  const int b = bh / Hh, h = bh % Hh;
  __shared__ float KVs[4096];
  __shared__ float Qs2[4096];
  const int tid = threadIdx.x;
  const int n0 = nc * 64;
#pragma unroll
  for (int it = 0; it < 4; ++it) {
    int i = it * 1024 + tid * 4;
    *(float4*)&KVs[i] = *(const float4*)&kv[(size_t)bh * 4096 + i];
    *(float4*)&Qs2[i] = *(const float4*)&qp[(size_t)(bh * Nn + n0) * 64 + i];
  }
  __syncthreads();
  const int c = tid & 63, rg = tid >> 6;
  for (int j = 0; j < 16; ++j) {
    int r = rg * 16 + j;
    float s = 0.f;
#pragma unroll
    for (int d = 0; d < 64; ++d) s += Qs2[r * 64 + d] * KVs[d * 64 + c];
    int ng = n0 + r;
    float rd = 1.0f / denom[bh * Nn + ng];
    outpre[((size_t)b * Nn + ng) * Cc + h * Dd + c] = s * rd;
  }
}

extern "C" void kernel_launch(void* const* d_in, const int* in_sizes, int n_in,
                              void* d_out, int out_size, void* d_ws, size_t ws_size,
                              hipStream_t stream) {
  const float* x = (const float*)d_in[0];
  const float* w_qkv = (const float*)d_in[1];
  const float* w_proj = (const float*)d_in[2];
  const float* b_proj = (const float*)d_in[3];
  float* out = (float*)d_out;
  float* attn = out + (size_t)Bb * Nn * Cc;  // second tuple element

  float* ws = (float*)d_ws;
  float* qkv = ws;                       // 9437184
  float* qp = qkv + (size_t)9437184;     // 3145728
  float* kp = qp + (size_t)3145728;      // 3145728
  float* kvpart = kp + (size_t)3145728;  // 1572864
  float* kspart = kvpart + (size_t)1572864;  // 24576
  float* kv = kspart + (size_t)24576;        // 98304
  float* ksum = kv + (size_t)98304;          // 1536
  float* denom = ksum + (size_t)1536;        // 49152
  float* outpre = denom + (size_t)49152;     // 3145728

  gemm64<false><<<dim3(TC / 64, (Bb * Nn) / 64), BDIM, 0, stream>>>(
      x, w_qkv, nullptr, qkv, Bb * Nn, Cc, TC);
  qk_transform<<<dim3(2 * BH * Nn * (Dd / 4) / BDIM), BDIM, 0, stream>>>(qkv, qp, kp);
  kv_partial<<<dim3(NCHUNK, BH), BDIM, 0, stream>>>(kp, qkv, kvpart, kspart);
  kv_reduce<<<dim3(BH), BDIM, 0, stream>>>(kvpart, kspart, kv, ksum);
  denom_kernel<<<dim3(Nn / BDIM, BH), BDIM, 0, stream>>>(qp, ksum, denom);
  attn_kernel<<<dim3(Nn / 64, Nn / 64, BH), BDIM, 0, stream>>>(qp, kp, denom, attn);
  outpre_kernel<<<dim3(Nn / 64, BH), BDIM, 0, stream>>>(qp, kv, denom, outpre);
  gemm64<true><<<dim3(Cc / 64, (Bb * Nn) / 64), BDIM, 0, stream>>>(
      outpre, w_proj, b_proj, out, Bb * Nn, Cc, Cc);
}

// Round 3
// 272.487 us; speedup vs baseline: 1.8681x; 1.8681x over previous
//
#include <hip/hip_runtime.h>
#include <hip/hip_bf16.h>
#include <cstdint>
#include <cmath>

#define BDIM 256

constexpr int Bb = 2;
constexpr int Nn = 2048;
constexpr int Cc = 768;
constexpr int Hh = 12;
constexpr int Dd = 64;
constexpr int TC = 3 * Cc;   // 2304
constexpr int BH = Bb * Hh;  // 24
constexpr int NCHUNK = 16;
constexpr int CHROWS = Nn / NCHUNK;  // 128

typedef __attribute__((ext_vector_type(8))) short short8v;   // 8 bf16 (4 VGPR)
typedef __attribute__((ext_vector_type(4))) float f32x4;

__device__ __forceinline__ float elu1(float x) {
  return x > 0.f ? x + 1.f : expf(x);
}

__device__ __forceinline__ unsigned short f2bf(float f) {
  uint32_t u = __float_as_uint(f);
  uint32_t r = (u + 0x7fff + ((u >> 16) & 1)) >> 16;
  return (unsigned short)r;
}
__device__ __forceinline__ float bf2f(unsigned short h) {
  return __uint_as_float(((uint32_t)h) << 16);
}

// ---------------- fp32 -> bf16 hi/lo split (elementwise) -----------------------------
__global__ __launch_bounds__(BDIM) void split_plain(const float* __restrict__ in,
                                                    unsigned short* __restrict__ hi,
                                                    unsigned short* __restrict__ lo) {
  int i = (blockIdx.x * BDIM + threadIdx.x) * 4;
  float4 v = *(const float4*)&in[i];
  ushort4 h, l;
  h.x = f2bf(v.x); l.x = f2bf(v.x - bf2f(h.x));
  h.y = f2bf(v.y); l.y = f2bf(v.y - bf2f(h.y));
  h.z = f2bf(v.z); l.z = f2bf(v.z - bf2f(h.z));
  h.w = f2bf(v.w); l.w = f2bf(v.w - bf2f(h.w));
  *(ushort4*)&hi[i] = h;
  *(ushort4*)&lo[i] = l;
}

// ---------------- fp32 [K][N] -> bf16 hi/lo transposed [N][K] ------------------------
__global__ __launch_bounds__(BDIM) void splitT(const float* __restrict__ W,
                                               unsigned short* __restrict__ Wh,
                                               unsigned short* __restrict__ Wl,
                                               int K, int N) {
  __shared__ float t[32][33];
  const int n0 = blockIdx.x * 32, k0 = blockIdx.y * 32;
  const int r = threadIdx.x >> 3, c4 = (threadIdx.x & 7) * 4;
  float4 v = *(const float4*)&W[(size_t)(k0 + r) * N + n0 + c4];
  t[r][c4 + 0] = v.x;
  t[r][c4 + 1] = v.y;
  t[r][c4 + 2] = v.z;
  t[r][c4 + 3] = v.w;
  __syncthreads();
  const int n = threadIdx.x >> 3, k4 = (threadIdx.x & 7) * 4;
  ushort4 h, l;
  float f0 = t[k4 + 0][n], f1 = t[k4 + 1][n], f2 = t[k4 + 2][n], f3 = t[k4 + 3][n];
  h.x = f2bf(f0); l.x = f2bf(f0 - bf2f(h.x));
  h.y = f2bf(f1); l.y = f2bf(f1 - bf2f(h.y));
  h.z = f2bf(f2); l.z = f2bf(f2 - bf2f(h.z));
  h.w = f2bf(f3); l.w = f2bf(f3 - bf2f(h.w));
  *(ushort4*)&Wh[(size_t)(n0 + n) * K + k0 + k4] = h;
  *(ushort4*)&Wl[(size_t)(n0 + n) * K + k0 + k4] = l;
}

// ---------------- MFMA GEMM: C[z] = A[z][MxK] * BT[z][NxK]^T (+bias) (/denom) --------
// A row-major [M][K] bf16 (hi/lo), BT row-major [N][K] bf16 (hi/lo) = B^T.
// TERMS=3: Ah*Bh + Ah*Bl + Al*Bh (fp32-grade).  TERMS=1: Ah*Bh only.
template <int TERMS, bool BIAS, bool DIV>
__global__ __launch_bounds__(BDIM) void mfma_gemm(
    const unsigned short* __restrict__ Ah, const unsigned short* __restrict__ Al,
    const unsigned short* __restrict__ BTh, const unsigned short* __restrict__ BTl,
    const float* __restrict__ bias, const float* __restrict__ denom,
    float* __restrict__ C, int M, int Nw, int K,
    long sAz, long sBz, long sCz) {
  constexpr int BK = 32;
  constexpr int LR = 40;  // padded LDS row (ushorts)
  __shared__ unsigned short lds[(TERMS == 3 ? 4 : 2) * 128 * LR];
  unsigned short* As_h = lds;
  unsigned short* Bs_h = lds + 128 * LR;
  unsigned short* As_l = (TERMS == 3) ? lds + 2 * 128 * LR : lds;
  unsigned short* Bs_l = (TERMS == 3) ? lds + 3 * 128 * LR : lds;

  const int z = blockIdx.z;
  const unsigned short* A = Ah + (size_t)z * sAz;
  const unsigned short* BT = BTh + (size_t)z * sBz;
  float* Cz = C + (size_t)z * sCz;

  const int tid = threadIdx.x;
  const int wave = tid >> 6, lane = tid & 63;
  const int wr = wave >> 1, wc = wave & 1;
  const int row0 = blockIdx.y * 128, col0 = blockIdx.x * 128;
  const int l15 = lane & 15, l4 = lane >> 4;
  const int kloc = l4 * 8;

  f32x4 acc[4][4];
#pragma unroll
  for (int i = 0; i < 4; ++i)
#pragma unroll
    for (int j = 0; j < 4; ++j) acc[i][j] = {0.f, 0.f, 0.f, 0.f};

  for (int k0 = 0; k0 < K; k0 += BK) {
    __syncthreads();
#pragma unroll
    for (int s = 0; s < 2; ++s) {
      int c = s * BDIM + tid;
      int r = c >> 2, k8 = (c & 3) * 8;
      *(uint4*)&As_h[r * LR + k8] = *(const uint4*)&A[(size_t)(row0 + r) * K + k0 + k8];
      *(uint4*)&Bs_h[r * LR + k8] = *(const uint4*)&BT[(size_t)(col0 + r) * K + k0 + k8];
      if constexpr (TERMS == 3) {
        const unsigned short* A2 = Al + (size_t)z * sAz;
        const unsigned short* BT2 = BTl + (size_t)z * sBz;
        *(uint4*)&As_l[r * LR + k8] = *(const uint4*)&A2[(size_t)(row0 + r) * K + k0 + k8];
        *(uint4*)&Bs_l[r * LR + k8] = *(const uint4*)&BT2[(size_t)(col0 + r) * K + k0 + k8];
      }
    }
    __syncthreads();

    short8v ah[4], bh[4];
#pragma unroll
    for (int i = 0; i < 4; ++i)
      ah[i] = *(const short8v*)&As_h[(wr * 64 + i * 16 + l15) * LR + kloc];
#pragma unroll
    for (int j = 0; j < 4; ++j)
      bh[j] = *(const short8v*)&Bs_h[(wc * 64 + j * 16 + l15) * LR + kloc];
#pragma unroll
    for (int i = 0; i < 4; ++i)
#pragma unroll
      for (int j = 0; j < 4; ++j)
        acc[i][j] = __builtin_amdgcn_mfma_f32_16x16x32_bf16(ah[i], bh[j], acc[i][j], 0, 0, 0);
    if constexpr (TERMS == 3) {
      short8v al[4], bl[4];
#pragma unroll
      for (int i = 0; i < 4; ++i)
        al[i] = *(const short8v*)&As_l[(wr * 64 + i * 16 + l15) * LR + kloc];
#pragma unroll
      for (int j = 0; j < 4; ++j)
        bl[j] = *(const short8v*)&Bs_l[(wc * 64 + j * 16 + l15) * LR + kloc];
#pragma unroll
      for (int i = 0; i < 4; ++i)
#pragma unroll
        for (int j = 0; j < 4; ++j) {
          acc[i][j] = __builtin_amdgcn_mfma_f32_16x16x32_bf16(ah[i], bl[j], acc[i][j], 0, 0, 0);
          acc[i][j] = __builtin_amdgcn_mfma_f32_16x16x32_bf16(al[i], bh[j], acc[i][j], 0, 0, 0);
        }
    }
  }

  // epilogue: C/D layout col=lane&15, row=(lane>>4)*4+reg
#pragma unroll
  for (int i = 0; i < 4; ++i) {
    const int rbase = row0 + wr * 64 + i * 16 + l4 * 4;
    float rd[4];
    if (DIV) {
#pragma unroll
      for (int r = 0; r < 4; ++r) rd[r] = 1.0f / denom[(size_t)z * M + rbase + r];
    }
#pragma unroll
    for (int j = 0; j < 4; ++j) {
      const int col = col0 + wc * 64 + j * 16 + l15;
      float bs = BIAS ? bias[col] : 0.f;
#pragma unroll
      for (int r = 0; r < 4; ++r) {
        float o = acc[i][j][r];
        if (DIV) o *= rd[r];
        if (BIAS) o += bs;
        Cz[(size_t)(rbase + r) * Nw + col] = o;
      }
    }
  }
}

// ---------------- qkv -> q',k' (fp32 + bf16) in [B,H,N,D] layout ---------------------
__global__ __launch_bounds__(BDIM) void qk_transform(const float* __restrict__ qkv,
                                                     float* __restrict__ qp,
                                                     float* __restrict__ kp,
                                                     unsigned short* __restrict__ qpb,
                                                     unsigned short* __restrict__ kpb) {
  const int per = BH * Nn * (Dd / 4);  // 786432
  int i = blockIdx.x * BDIM + threadIdx.x;
  int tt = i / per;
  int r = i - tt * per;
  int d4 = r & 15;
  int t = r >> 4;
  int n = t & (Nn - 1);
  t >>= 11;
  int h = t % Hh;
  int b = t / Hh;
  float4 v = *(const float4*)&qkv[(size_t)(b * Nn + n) * TC + tt * Cc + h * Dd + d4 * 4];
  float4 o;
  o.x = elu1(v.x);
  o.y = elu1(v.y);
  o.z = elu1(v.z);
  o.w = elu1(v.w);
  float* dst = tt ? kp : qp;
  unsigned short* dstb = tt ? kpb : qpb;
  *(float4*)&dst[(size_t)r * 4] = o;
  ushort4 ob;
  ob.x = f2bf(o.x);
  ob.y = f2bf(o.y);
  ob.z = f2bf(o.z);
  ob.w = f2bf(o.w);
  *(ushort4*)&dstb[(size_t)r * 4] = ob;
}

// ---------------- partial KV = k'^T v  and  Ksum = sum_n k' --------------------------
__global__ __launch_bounds__(BDIM) void kv_partial(const float* __restrict__ kp,
                                                   const float* __restrict__ qkv,
                                                   float* __restrict__ kvpart,
                                                   float* __restrict__ kspart) {
  const int chunk = blockIdx.x, bh = blockIdx.y;
  const int b = bh / Hh, h = bh % Hh;
  __shared__ float ks[8][64];
  __shared__ float vs[8][64];
  const int tid = threadIdx.x;
  const int nn = tid >> 5, f2 = (tid & 31) << 1;
  const int e = tid & 63, dg = tid >> 6;
  float acc[16] = {};
  float ksacc = 0.f;
  const int n0base = chunk * CHROWS;
  for (int s = 0; s < CHROWS; s += 8) {
    int n = n0base + s + nn;
    float2 k2 = *(const float2*)&kp[(size_t)(bh * Nn + n) * 64 + f2];
    float2 v2 = *(const float2*)&qkv[(size_t)(b * Nn + n) * TC + 2 * Cc + h * Dd + f2];
    __syncthreads();
    *(float2*)&ks[nn][f2] = k2;
    *(float2*)&vs[nn][f2] = v2;
    __syncthreads();
#pragma unroll
    for (int j = 0; j < 8; ++j) {
      float vv = vs[j][e];
#pragma unroll
      for (int d = 0; d < 16; ++d) acc[d] += ks[j][dg * 16 + d] * vv;
      if (tid < 64) ksacc += ks[j][tid];
    }
  }
  float* outp = kvpart + (size_t)(bh * NCHUNK + chunk) * 4096;
#pragma unroll
  for (int d = 0; d < 16; ++d) outp[(dg * 16 + d) * 64 + e] = acc[d];
  if (tid < 64) kspart[(bh * NCHUNK + chunk) * 64 + tid] = ksacc;
}

__global__ __launch_bounds__(BDIM) void kv_reduce(const float* __restrict__ kvpart,
                                                  const float* __restrict__ kspart,
                                                  float* __restrict__ kv,
                                                  float* __restrict__ ksum) {
  const int bh = blockIdx.x, tid = threadIdx.x;
#pragma unroll
  for (int i = 0; i < 16; ++i) {
    int idx = i * 256 + tid;
    float s = 0.f;
    for (int c = 0; c < NCHUNK; ++c) s += kvpart[(size_t)(bh * NCHUNK + c) * 4096 + idx];
    kv[(size_t)bh * 4096 + idx] = s;
  }
  if (tid < 64) {
    float s = 0.f;
    for (int c = 0; c < NCHUNK; ++c) s += kspart[(bh * NCHUNK + c) * 64 + tid];
    ksum[bh * 64 + tid] = s;
  }
}

// ---------------- denom[b,h,n] = q' . Ksum -------------------------------------------
__global__ __launch_bounds__(BDIM) void denom_kernel(const float* __restrict__ qp,
                                                     const float* __restrict__ ksum,
                                                     float* __restrict__ denom) {
  const int bh = blockIdx.y;
  const int n = blockIdx.x * BDIM + threadIdx.x;
  __shared__ float kss[64];
  if (threadIdx.x < 64) kss[threadIdx.x] = ksum[bh * 64 + threadIdx.x];
  __syncthreads();
  const float* qrow = qp + (size_t)(bh * Nn + n) * 64;
  float s = 0.f;
#pragma unroll
  for (int d4 = 0; d4 < 16; ++d4) {
    float4 q = *(const float4*)(qrow + d4 * 4);
    s += q.x * kss[d4 * 4] + q.y * kss[d4 * 4 + 1] + q.z * kss[d4 * 4 + 2] +
         q.w * kss[d4 * 4 + 3];
  }
  denom[bh * Nn + n] = s;
}

// ---------------- out_pre[b,n,h*64+c] = (q' . KV[:,c]) / denom -----------------------
__global__ __launch_bounds__(BDIM) void outpre_kernel(const float* __restrict__ qp,
                                                      const float* __restrict__ kv,
                                                      const float* __restrict__ denom,
                                                      float* __restrict__ outpre) {
  const int nc = blockIdx.x, bh = blockIdx.y;
  const int b = bh / Hh, h = bh % Hh;
  __shared__ float KVs[4096];
  __shared__ float Qs2[4096];
  const int tid = threadIdx.x;
  const int n0 = nc * 64;
#pragma unroll
  for (int it = 0; it < 4; ++it) {
    int i = it * 1024 + tid * 4;
    *(float4*)&KVs[i] = *(const float4*)&kv[(size_t)bh * 4096 + i];
    *(float4*)&Qs2[i] = *(const float4*)&qp[(size_t)(bh * Nn + n0) * 64 + i];
  }
  __syncthreads();
  const int c = tid & 63, rg = tid >> 6;
  for (int j = 0; j < 16; ++j) {
    int r = rg * 16 + j;
    float s = 0.f;
#pragma unroll
    for (int d = 0; d < 64; ++d) s += Qs2[r * 64 + d] * KVs[d * 64 + c];
    int ng = n0 + r;
    float rd = 1.0f / denom[bh * Nn + ng];
    outpre[((size_t)b * Nn + ng) * Cc + h * Dd + c] = s * rd;
  }
}

extern "C" void kernel_launch(void* const* d_in, const int* in_sizes, int n_in,
                              void* d_out, int out_size, void* d_ws, size_t ws_size,
                              hipStream_t stream) {
  const float* x = (const float*)d_in[0];
  const float* w_qkv = (const float*)d_in[1];
  const float* w_proj = (const float*)d_in[2];
  const float* b_proj = (const float*)d_in[3];
  float* out = (float*)d_out;
  float* attn = out + (size_t)Bb * Nn * Cc;

  float* ws = (float*)d_ws;
  float* qkv = ws;                           // 9437184
  float* qp = qkv + 9437184;                 // 3145728
  float* kp = qp + 3145728;                  // 3145728
  float* kvpart = kp + 3145728;              // 1572864
  float* kspart = kvpart + 1572864;          // 24576
  float* kvm = kspart + 24576;               // 98304
  float* ksum = kvm + 98304;                 // 2048 (padded)
  float* denom = ksum + 2048;                // 49152
  float* outpre = denom + 49152;             // 3145728
  unsigned short* us = (unsigned short*)(outpre + 3145728);
  unsigned short* xh = us;                   // 3145728
  unsigned short* xl = xh + 3145728;
  unsigned short* wqh = xl + 3145728;        // 1769472
  unsigned short* wql = wqh + 1769472;
  unsigned short* qpb = wql + 1769472;       // 3145728
  unsigned short* kpb = qpb + 3145728;
  unsigned short* oph = kpb + 3145728;       // 3145728
  unsigned short* opl = oph + 3145728;
  unsigned short* wph = opl + 3145728;       // 589824
  unsigned short* wpl = wph + 589824;

  // qkv = x @ w_qkv  (split bf16 MFMA, fp32-grade)
  split_plain<<<dim3(3072), BDIM, 0, stream>>>(x, xh, xl);
  splitT<<<dim3(TC / 32, Cc / 32), BDIM, 0, stream>>>(w_qkv, wqh, wql, Cc, TC);
  mfma_gemm<3, false, false><<<dim3(TC / 128, 32, 1), BDIM, 0, stream>>>(
      xh, xl, wqh, wql, nullptr, nullptr, qkv, Bb * Nn, TC, Cc, 0, 0, 0);

  qk_transform<<<dim3(6144), BDIM, 0, stream>>>(qkv, qp, kp, qpb, kpb);
  kv_partial<<<dim3(NCHUNK, BH), BDIM, 0, stream>>>(kp, qkv, kvpart, kspart);
  kv_reduce<<<dim3(BH), BDIM, 0, stream>>>(kvpart, kspart, kvm, ksum);
  denom_kernel<<<dim3(Nn / BDIM, BH), BDIM, 0, stream>>>(qp, ksum, denom);

  // attn = (Q' K'^T) / denom  (single-term bf16 MFMA; abs err ~2e-6)
  mfma_gemm<1, false, true><<<dim3(Nn / 128, Nn / 128, BH), BDIM, 0, stream>>>(
      qpb, nullptr, kpb, nullptr, nullptr, denom, attn, Nn, Nn, Dd,
      (long)Nn * Dd, (long)Nn * Dd, (long)Nn * Nn);

  outpre_kernel<<<dim3(Nn / 64, BH), BDIM, 0, stream>>>(qp, kvm, denom, outpre);

  // out = outpre @ w_proj + b_proj  (split bf16 MFMA)
  split_plain<<<dim3(3072), BDIM, 0, stream>>>(outpre, oph, opl);
  splitT<<<dim3(Cc / 32, Cc / 32), BDIM, 0, stream>>>(w_proj, wph, wpl, Cc, Cc);
  mfma_gemm<3, true, false><<<dim3(Cc / 128, 32, 1), BDIM, 0, stream>>>(
      oph, opl, wph, wpl, b_proj, nullptr, out, Bb * Nn, Cc, Cc, 0, 0, 0);
}

// Round 4
// 256.898 us; speedup vs baseline: 1.9815x; 1.0607x over previous
//
#include <hip/hip_runtime.h>
#include <hip/hip_bf16.h>
#include <cstdint>
#include <cmath>

#define BDIM 256

constexpr int Bb = 2;
constexpr int Nn = 2048;
constexpr int Cc = 768;
constexpr int Hh = 12;
constexpr int Dd = 64;
constexpr int TC = 3 * Cc;   // 2304
constexpr int BH = Bb * Hh;  // 24
constexpr int NCHUNK = 16;
constexpr int CHROWS = Nn / NCHUNK;  // 128

typedef __attribute__((ext_vector_type(8))) short short8v;   // 8 bf16 (4 VGPR)
typedef __attribute__((ext_vector_type(4))) float f32x4;

__device__ __forceinline__ float elu1(float x) {
  return x > 0.f ? x + 1.f : expf(x);
}

__device__ __forceinline__ unsigned short f2bf(float f) {
  uint32_t u = __float_as_uint(f);
  uint32_t r = (u + 0x7fff + ((u >> 16) & 1)) >> 16;
  return (unsigned short)r;
}
__device__ __forceinline__ float bf2f(unsigned short h) {
  return __uint_as_float(((uint32_t)h) << 16);
}

// async global->LDS, 16 B per lane; lds base must be wave-uniform (HW adds lane*16)
__device__ __forceinline__ void gll16(const unsigned short* g, unsigned short* ldsbase) {
  __builtin_amdgcn_global_load_lds((const __attribute__((address_space(1))) void*)g,
                                   (__attribute__((address_space(3))) void*)ldsbase,
                                   16, 0, 0);
}

// ---------------- fp32 -> bf16 hi/lo split (elementwise) -----------------------------
__global__ __launch_bounds__(BDIM) void split_plain(const float* __restrict__ in,
                                                    unsigned short* __restrict__ hi,
                                                    unsigned short* __restrict__ lo) {
  int i = (blockIdx.x * BDIM + threadIdx.x) * 4;
  float4 v = *(const float4*)&in[i];
  ushort4 h, l;
  h.x = f2bf(v.x); l.x = f2bf(v.x - bf2f(h.x));
  h.y = f2bf(v.y); l.y = f2bf(v.y - bf2f(h.y));
  h.z = f2bf(v.z); l.z = f2bf(v.z - bf2f(h.z));
  h.w = f2bf(v.w); l.w = f2bf(v.w - bf2f(h.w));
  *(ushort4*)&hi[i] = h;
  *(ushort4*)&lo[i] = l;
}

// ---------------- fp32 [K][N] -> bf16 hi/lo transposed [N][K] ------------------------
__global__ __launch_bounds__(BDIM) void splitT(const float* __restrict__ W,
                                               unsigned short* __restrict__ Wh,
                                               unsigned short* __restrict__ Wl,
                                               int K, int N) {
  __shared__ float t[32][33];
  const int n0 = blockIdx.x * 32, k0 = blockIdx.y * 32;
  const int r = threadIdx.x >> 3, c4 = (threadIdx.x & 7) * 4;
  float4 v = *(const float4*)&W[(size_t)(k0 + r) * N + n0 + c4];
  t[r][c4 + 0] = v.x;
  t[r][c4 + 1] = v.y;
  t[r][c4 + 2] = v.z;
  t[r][c4 + 3] = v.w;
  __syncthreads();
  const int n = threadIdx.x >> 3, k4 = (threadIdx.x & 7) * 4;
  ushort4 h, l;
  float f0 = t[k4 + 0][n], f1 = t[k4 + 1][n], f2 = t[k4 + 2][n], f3 = t[k4 + 3][n];
  h.x = f2bf(f0); l.x = f2bf(f0 - bf2f(h.x));
  h.y = f2bf(f1); l.y = f2bf(f1 - bf2f(h.y));
  h.z = f2bf(f2); l.z = f2bf(f2 - bf2f(h.z));
  h.w = f2bf(f3); l.w = f2bf(f3 - bf2f(h.w));
  *(ushort4*)&Wh[(size_t)(n0 + n) * K + k0 + k4] = h;
  *(ushort4*)&Wl[(size_t)(n0 + n) * K + k0 + k4] = l;
}

// ---------------- MFMA GEMM (m97-style): C[z] = A[z][MxK] * BT[z][NxK]^T -------------
// Linear LDS [128][32] per matrix, global_load_lds width-16 staging, BK=32.
// TERMS=3: Ah*Bh + Ah*Bl + Al*Bh (fp32-grade).  TERMS=1: Ah*Bh only.
template <int TERMS, bool BIAS, bool DIV>
__global__ __launch_bounds__(BDIM) void mfma_gemm(
    const unsigned short* __restrict__ Ah, const unsigned short* __restrict__ Al,
    const unsigned short* __restrict__ BTh, const unsigned short* __restrict__ BTl,
    const float* __restrict__ bias, const float* __restrict__ denom,
    float* __restrict__ C, int M, int Nw, int K,
    long sAz, long sBz, long sCz) {
  constexpr int NMAT = (TERMS == 3) ? 4 : 2;
  __shared__ unsigned short lds[NMAT * 4096];  // per matrix: [128][32] ushort = 8 KB

  const int z = blockIdx.z;
  const unsigned short* A0 = Ah + (size_t)z * sAz;
  const unsigned short* B0 = BTh + (size_t)z * sBz;
  float* Cz = C + (size_t)z * sCz;

  const int tid = threadIdx.x;
  const int wave = tid >> 6, lane = tid & 63;
  const int wr = wave >> 1, wc = wave & 1;
  const int row0 = blockIdx.y * 128, col0 = blockIdx.x * 128;
  const int l15 = lane & 15, l4 = lane >> 4;

  // staging geometry: per issue, 256 lanes x 16B = 64 rows of 32 bf16
  const int srow = wave * 16 + (lane >> 2);  // row within 64-row half
  const int scol = (lane & 3) * 8;           // k element offset
  const int wbase = wave * 512;              // ushort offset of wave's LDS chunk

  f32x4 acc[4][4];
#pragma unroll
  for (int i = 0; i < 4; ++i)
#pragma unroll
    for (int j = 0; j < 4; ++j) acc[i][j] = {0.f, 0.f, 0.f, 0.f};

  for (int k0 = 0; k0 < K; k0 += 32) {
    __syncthreads();  // previous compute done before overwrite
    gll16(&A0[(size_t)(row0 + srow) * K + k0 + scol], lds + wbase);
    gll16(&A0[(size_t)(row0 + 64 + srow) * K + k0 + scol], lds + 2048 + wbase);
    gll16(&B0[(size_t)(col0 + srow) * K + k0 + scol], lds + 4096 + wbase);
    gll16(&B0[(size_t)(col0 + 64 + srow) * K + k0 + scol], lds + 4096 + 2048 + wbase);
    if constexpr (TERMS == 3) {
      const unsigned short* A1 = Al + (size_t)z * sAz;
      const unsigned short* B1 = BTl + (size_t)z * sBz;
      gll16(&A1[(size_t)(row0 + srow) * K + k0 + scol], lds + 8192 + wbase);
      gll16(&A1[(size_t)(row0 + 64 + srow) * K + k0 + scol], lds + 8192 + 2048 + wbase);
      gll16(&B1[(size_t)(col0 + srow) * K + k0 + scol], lds + 12288 + wbase);
      gll16(&B1[(size_t)(col0 + 64 + srow) * K + k0 + scol], lds + 12288 + 2048 + wbase);
    }
    __syncthreads();  // compiler drains vmcnt(0) before barrier

    short8v ah[4], bh[4];
#pragma unroll
    for (int i = 0; i < 4; ++i)
      ah[i] = *(const short8v*)&lds[(wr * 64 + i * 16 + l15) * 32 + l4 * 8];
#pragma unroll
    for (int j = 0; j < 4; ++j)
      bh[j] = *(const short8v*)&lds[4096 + (wc * 64 + j * 16 + l15) * 32 + l4 * 8];
#pragma unroll
    for (int i = 0; i < 4; ++i)
#pragma unroll
      for (int j = 0; j < 4; ++j)
        acc[i][j] = __builtin_amdgcn_mfma_f32_16x16x32_bf16(ah[i], bh[j], acc[i][j], 0, 0, 0);
    if constexpr (TERMS == 3) {
      short8v al[4], bl[4];
#pragma unroll
      for (int i = 0; i < 4; ++i)
        al[i] = *(const short8v*)&lds[8192 + (wr * 64 + i * 16 + l15) * 32 + l4 * 8];
#pragma unroll
      for (int j = 0; j < 4; ++j)
        bl[j] = *(const short8v*)&lds[12288 + (wc * 64 + j * 16 + l15) * 32 + l4 * 8];
#pragma unroll
      for (int i = 0; i < 4; ++i)
#pragma unroll
        for (int j = 0; j < 4; ++j) {
          acc[i][j] = __builtin_amdgcn_mfma_f32_16x16x32_bf16(ah[i], bl[j], acc[i][j], 0, 0, 0);
          acc[i][j] = __builtin_amdgcn_mfma_f32_16x16x32_bf16(al[i], bh[j], acc[i][j], 0, 0, 0);
        }
    }
  }

  // epilogue: C/D layout col=lane&15, row=(lane>>4)*4+reg
#pragma unroll
  for (int i = 0; i < 4; ++i) {
    const int rbase = row0 + wr * 64 + i * 16 + l4 * 4;
    float rd[4];
    if (DIV) {
#pragma unroll
      for (int r = 0; r < 4; ++r) rd[r] = 1.0f / denom[(size_t)z * M + rbase + r];
    }
#pragma unroll
    for (int j = 0; j < 4; ++j) {
      const int col = col0 + wc * 64 + j * 16 + l15;
      float bs = BIAS ? bias[col] : 0.f;
#pragma unroll
      for (int r = 0; r < 4; ++r) {
        float o = acc[i][j][r];
        if (DIV) o *= rd[r];
        if (BIAS) o += bs;
        Cz[(size_t)(rbase + r) * Nw + col] = o;
      }
    }
  }
}

// ---------------- qkv -> q',k' (fp32 + bf16) in [B,H,N,D] layout ---------------------
__global__ __launch_bounds__(BDIM) void qk_transform(const float* __restrict__ qkv,
                                                     float* __restrict__ qp,
                                                     float* __restrict__ kp,
                                                     unsigned short* __restrict__ qpb,
                                                     unsigned short* __restrict__ kpb) {
  const int per = BH * Nn * (Dd / 4);  // 786432
  int i = blockIdx.x * BDIM + threadIdx.x;
  int tt = i / per;
  int r = i - tt * per;
  int d4 = r & 15;
  int t = r >> 4;
  int n = t & (Nn - 1);
  t >>= 11;
  int h = t % Hh;
  int b = t / Hh;
  float4 v = *(const float4*)&qkv[(size_t)(b * Nn + n) * TC + tt * Cc + h * Dd + d4 * 4];
  float4 o;
  o.x = elu1(v.x);
  o.y = elu1(v.y);
  o.z = elu1(v.z);
  o.w = elu1(v.w);
  float* dst = tt ? kp : qp;
  unsigned short* dstb = tt ? kpb : qpb;
  *(float4*)&dst[(size_t)r * 4] = o;
  ushort4 ob;
  ob.x = f2bf(o.x);
  ob.y = f2bf(o.y);
  ob.z = f2bf(o.z);
  ob.w = f2bf(o.w);
  *(ushort4*)&dstb[(size_t)r * 4] = ob;
}

// ---------------- partial KV = k'^T v  and  Ksum = sum_n k' --------------------------
__global__ __launch_bounds__(BDIM) void kv_partial(const float* __restrict__ kp,
                                                   const float* __restrict__ qkv,
                                                   float* __restrict__ kvpart,
                                                   float* __restrict__ kspart) {
  const int chunk = blockIdx.x, bh = blockIdx.y;
  const int b = bh / Hh, h = bh % Hh;
  __shared__ float ks[8][64];
  __shared__ float vs[8][64];
  const int tid = threadIdx.x;
  const int nn = tid >> 5, f2 = (tid & 31) << 1;
  const int e = tid & 63, dg = tid >> 6;
  float acc[16] = {};
  float ksacc = 0.f;
  const int n0base = chunk * CHROWS;
  for (int s = 0; s < CHROWS; s += 8) {
    int n = n0base + s + nn;
    float2 k2 = *(const float2*)&kp[(size_t)(bh * Nn + n) * 64 + f2];
    float2 v2 = *(const float2*)&qkv[(size_t)(b * Nn + n) * TC + 2 * Cc + h * Dd + f2];
    __syncthreads();
    *(float2*)&ks[nn][f2] = k2;
    *(float2*)&vs[nn][f2] = v2;
    __syncthreads();
#pragma unroll
    for (int j = 0; j < 8; ++j) {
      float vv = vs[j][e];
#pragma unroll
      for (int d = 0; d < 16; ++d) acc[d] += ks[j][dg * 16 + d] * vv;
      if (tid < 64) ksacc += ks[j][tid];
    }
  }
  float* outp = kvpart + (size_t)(bh * NCHUNK + chunk) * 4096;
#pragma unroll
  for (int d = 0; d < 16; ++d) outp[(dg * 16 + d) * 64 + e] = acc[d];
  if (tid < 64) kspart[(bh * NCHUNK + chunk) * 64 + tid] = ksacc;
}

__global__ __launch_bounds__(BDIM) void kv_reduce(const float* __restrict__ kvpart,
                                                  const float* __restrict__ kspart,
                                                  float* __restrict__ kv,
                                                  float* __restrict__ ksum) {
  const int bh = blockIdx.x, tid = threadIdx.x;
#pragma unroll
  for (int i = 0; i < 16; ++i) {
    int idx = i * 256 + tid;
    float s = 0.f;
    for (int c = 0; c < NCHUNK; ++c) s += kvpart[(size_t)(bh * NCHUNK + c) * 4096 + idx];
    kv[(size_t)bh * 4096 + idx] = s;
  }
  if (tid < 64) {
    float s = 0.f;
    for (int c = 0; c < NCHUNK; ++c) s += kspart[(bh * NCHUNK + c) * 64 + tid];
    ksum[bh * 64 + tid] = s;
  }
}

// ---------------- denom[b,h,n] = q' . Ksum -------------------------------------------
__global__ __launch_bounds__(BDIM) void denom_kernel(const float* __restrict__ qp,
                                                     const float* __restrict__ ksum,
                                                     float* __restrict__ denom) {
  const int bh = blockIdx.y;
  const int n = blockIdx.x * BDIM + threadIdx.x;
  __shared__ float kss[64];
  if (threadIdx.x < 64) kss[threadIdx.x] = ksum[bh * 64 + threadIdx.x];
  __syncthreads();
  const float* qrow = qp + (size_t)(bh * Nn + n) * 64;
  float s = 0.f;
#pragma unroll
  for (int d4 = 0; d4 < 16; ++d4) {
    float4 q = *(const float4*)(qrow + d4 * 4);
    s += q.x * kss[d4 * 4] + q.y * kss[d4 * 4 + 1] + q.z * kss[d4 * 4 + 2] +
         q.w * kss[d4 * 4 + 3];
  }
  denom[bh * Nn + n] = s;
}

// ------ out_pre[b,n,h*64+c] = (q' . KV[:,c]) / denom, emitted as bf16 hi/lo ----------
__global__ __launch_bounds__(BDIM) void outpre_kernel(const float* __restrict__ qp,
                                                      const float* __restrict__ kv,
                                                      const float* __restrict__ denom,
                                                      unsigned short* __restrict__ oph,
                                                      unsigned short* __restrict__ opl) {
  const int nc = blockIdx.x, bh = blockIdx.y;
  const int b = bh / Hh, h = bh % Hh;
  __shared__ float KVs[4096];
  __shared__ float Qs2[4096];
  const int tid = threadIdx.x;
  const int n0 = nc * 64;
#pragma unroll
  for (int it = 0; it < 4; ++it) {
    int i = it * 1024 + tid * 4;
    *(float4*)&KVs[i] = *(const float4*)&kv[(size_t)bh * 4096 + i];
    *(float4*)&Qs2[i] = *(const float4*)&qp[(size_t)(bh * Nn + n0) * 64 + i];
  }
  __syncthreads();
  const int c = tid & 63, rg = tid >> 6;
  for (int j = 0; j < 16; ++j) {
    int r = rg * 16 + j;
    float s = 0.f;
#pragma unroll
    for (int d = 0; d < 64; ++d) s += Qs2[r * 64 + d] * KVs[d * 64 + c];
    int ng = n0 + r;
    float rd = 1.0f / denom[bh * Nn + ng];
    float o = s * rd;
    size_t idx = ((size_t)b * Nn + ng) * Cc + h * Dd + c;
    unsigned short hh = f2bf(o);
    oph[idx] = hh;
    opl[idx] = f2bf(o - bf2f(hh));
  }
}

extern "C" void kernel_launch(void* const* d_in, const int* in_sizes, int n_in,
                              void* d_out, int out_size, void* d_ws, size_t ws_size,
                              hipStream_t stream) {
  const float* x = (const float*)d_in[0];
  const float* w_qkv = (const float*)d_in[1];
  const float* w_proj = (const float*)d_in[2];
  const float* b_proj = (const float*)d_in[3];
  float* out = (float*)d_out;
  float* attn = out + (size_t)Bb * Nn * Cc;

  float* ws = (float*)d_ws;
  float* qkv = ws;                           // 9437184
  float* qp = qkv + 9437184;                 // 3145728
  float* kp = qp + 3145728;                  // 3145728
  float* kvpart = kp + 3145728;              // 1572864
  float* kspart = kvpart + 1572864;          // 24576
  float* kvm = kspart + 24576;               // 98304
  float* ksum = kvm + 98304;                 // 2048 (padded)
  float* denom = ksum + 2048;                // 49152
  float* outpre_unused = denom + 49152;      // 3145728 (kept for layout stability)
  unsigned short* us = (unsigned short*)(outpre_unused + 3145728);
  unsigned short* xh = us;                   // 3145728
  unsigned short* xl = xh + 3145728;
  unsigned short* wqh = xl + 3145728;        // 1769472
  unsigned short* wql = wqh + 1769472;
  unsigned short* qpb = wql + 1769472;       // 3145728
  unsigned short* kpb = qpb + 3145728;
  unsigned short* oph = kpb + 3145728;       // 3145728
  unsigned short* opl = oph + 3145728;
  unsigned short* wph = opl + 3145728;       // 589824
  unsigned short* wpl = wph + 589824;

  // qkv = x @ w_qkv  (split bf16 MFMA, fp32-grade)
  split_plain<<<dim3(3072), BDIM, 0, stream>>>(x, xh, xl);
  splitT<<<dim3(TC / 32, Cc / 32), BDIM, 0, stream>>>(w_qkv, wqh, wql, Cc, TC);
  mfma_gemm<3, false, false><<<dim3(TC / 128, 32, 1), BDIM, 0, stream>>>(
      xh, xl, wqh, wql, nullptr, nullptr, qkv, Bb * Nn, TC, Cc, 0, 0, 0);

  qk_transform<<<dim3(6144), BDIM, 0, stream>>>(qkv, qp, kp, qpb, kpb);
  kv_partial<<<dim3(NCHUNK, BH), BDIM, 0, stream>>>(kp, qkv, kvpart, kspart);
  kv_reduce<<<dim3(BH), BDIM, 0, stream>>>(kvpart, kspart, kvm, ksum);
  denom_kernel<<<dim3(Nn / BDIM, BH), BDIM, 0, stream>>>(qp, ksum, denom);

  // attn = (Q' K'^T) / denom  (single-term bf16 MFMA; abs err ~2e-6)
  mfma_gemm<1, false, true><<<dim3(Nn / 128, Nn / 128, BH), BDIM, 0, stream>>>(
      qpb, nullptr, kpb, nullptr, nullptr, denom, attn, Nn, Nn, Dd,
      (long)Nn * Dd, (long)Nn * Dd, (long)Nn * Nn);

  outpre_kernel<<<dim3(Nn / 64, BH), BDIM, 0, stream>>>(qp, kvm, denom, oph, opl);

  // out = outpre @ w_proj + b_proj  (split bf16 MFMA)
  splitT<<<dim3(Cc / 32, Cc / 32), BDIM, 0, stream>>>(w_proj, wph, wpl, Cc, Cc);
  mfma_gemm<3, true, false><<<dim3(Cc / 128, 32, 1), BDIM, 0, stream>>>(
      oph, opl, wph, wpl, b_proj, nullptr, out, Bb * Nn, Cc, Cc, 0, 0, 0);
}

// Round 5
// 226.467 us; speedup vs baseline: 2.2477x; 1.1344x over previous
//
#include <hip/hip_runtime.h>
#include <hip/hip_bf16.h>
#include <cstdint>
#include <cmath>

#define BDIM 256

constexpr int Bb = 2;
constexpr int Nn = 2048;
constexpr int Cc = 768;
constexpr int Hh = 12;
constexpr int Dd = 64;
constexpr int TC = 3 * Cc;   // 2304
constexpr int BH = Bb * Hh;  // 24
constexpr int NCHUNK = 16;
constexpr int CHROWS = Nn / NCHUNK;  // 128

typedef __attribute__((ext_vector_type(8))) short short8v;   // 8 bf16 (4 VGPR)
typedef __attribute__((ext_vector_type(4))) float f32x4;

__device__ __forceinline__ float elu1(float x) {
  return x > 0.f ? x + 1.f : expf(x);
}

__device__ __forceinline__ unsigned short f2bf(float f) {
  uint32_t u = __float_as_uint(f);
  uint32_t r = (u + 0x7fff + ((u >> 16) & 1)) >> 16;
  return (unsigned short)r;
}
__device__ __forceinline__ float bf2f(unsigned short h) {
  return __uint_as_float(((uint32_t)h) << 16);
}

// async global->LDS, 16 B per lane; lds base must be wave-uniform (HW adds lane*16)
__device__ __forceinline__ void gll16(const unsigned short* g, unsigned short* ldsbase) {
  __builtin_amdgcn_global_load_lds((const __attribute__((address_space(1))) void*)g,
                                   (__attribute__((address_space(3))) void*)ldsbase,
                                   16, 0, 0);
}

// ---------------- fp32 -> bf16 cast (hi only) ----------------------------------------
__global__ __launch_bounds__(BDIM) void cast_bf16(const float* __restrict__ in,
                                                  unsigned short* __restrict__ hi) {
  int i = (blockIdx.x * BDIM + threadIdx.x) * 4;
  float4 v = *(const float4*)&in[i];
  ushort4 h;
  h.x = f2bf(v.x);
  h.y = f2bf(v.y);
  h.z = f2bf(v.z);
  h.w = f2bf(v.w);
  *(ushort4*)&hi[i] = h;
}

// ---------------- fp32 [K][N] -> bf16 hi/lo transposed [N][K] ------------------------
__global__ __launch_bounds__(BDIM) void splitT(const float* __restrict__ W,
                                               unsigned short* __restrict__ Wh,
                                               unsigned short* __restrict__ Wl,
                                               int K, int N) {
  __shared__ float t[32][33];
  const int n0 = blockIdx.x * 32, k0 = blockIdx.y * 32;
  const int r = threadIdx.x >> 3, c4 = (threadIdx.x & 7) * 4;
  float4 v = *(const float4*)&W[(size_t)(k0 + r) * N + n0 + c4];
  t[r][c4 + 0] = v.x;
  t[r][c4 + 1] = v.y;
  t[r][c4 + 2] = v.z;
  t[r][c4 + 3] = v.w;
  __syncthreads();
  const int n = threadIdx.x >> 3, k4 = (threadIdx.x & 7) * 4;
  ushort4 h, l;
  float f0 = t[k4 + 0][n], f1 = t[k4 + 1][n], f2 = t[k4 + 2][n], f3 = t[k4 + 3][n];
  h.x = f2bf(f0); l.x = f2bf(f0 - bf2f(h.x));
  h.y = f2bf(f1); l.y = f2bf(f1 - bf2f(h.y));
  h.z = f2bf(f2); l.z = f2bf(f2 - bf2f(h.z));
  h.w = f2bf(f3); l.w = f2bf(f3 - bf2f(h.w));
  *(ushort4*)&Wh[(size_t)(n0 + n) * K + k0 + k4] = h;
  *(ushort4*)&Wl[(size_t)(n0 + n) * K + k0 + k4] = l;
}

// ---------------- fused qkv GEMM: [q|k|v] = x @ w_qkv with elu+1 epilogue ------------
// A = xh [4096][768] bf16, BT = wqh [2304][768] bf16 (w_qkv^T). 1-term bf16.
// Epilogue writes qp/kp (fp32), qpb/kpb (bf16), vp (fp32) in [B,H,N,D] layout.
__global__ __launch_bounds__(BDIM) void gemm_qkv(
    const unsigned short* __restrict__ A0, const unsigned short* __restrict__ B0,
    float* __restrict__ qp, float* __restrict__ kp, float* __restrict__ vp,
    unsigned short* __restrict__ qpb, unsigned short* __restrict__ kpb) {
  constexpr int K = Cc;  // 768
  __shared__ unsigned short lds[8192];  // A:[128][32], B:[128][32]

  const int tid = threadIdx.x;
  const int wave = tid >> 6, lane = tid & 63;
  const int wr = wave >> 1, wc = wave & 1;
  const int row0 = blockIdx.y * 128, colblk = blockIdx.x;
  const int col0 = colblk * 128;
  const int l15 = lane & 15, l4 = lane >> 4;

  const int srow = wave * 16 + (lane >> 2);
  const int scol = (lane & 3) * 8;
  const int wbase = wave * 512;

  f32x4 acc[4][4];
#pragma unroll
  for (int i = 0; i < 4; ++i)
#pragma unroll
    for (int j = 0; j < 4; ++j) acc[i][j] = {0.f, 0.f, 0.f, 0.f};

  for (int k0 = 0; k0 < K; k0 += 32) {
    __syncthreads();
    gll16(&A0[(size_t)(row0 + srow) * K + k0 + scol], lds + wbase);
    gll16(&A0[(size_t)(row0 + 64 + srow) * K + k0 + scol], lds + 2048 + wbase);
    gll16(&B0[(size_t)(col0 + srow) * K + k0 + scol], lds + 4096 + wbase);
    gll16(&B0[(size_t)(col0 + 64 + srow) * K + k0 + scol], lds + 4096 + 2048 + wbase);
    __syncthreads();

    short8v ah[4], bh[4];
#pragma unroll
    for (int i = 0; i < 4; ++i)
      ah[i] = *(const short8v*)&lds[(wr * 64 + i * 16 + l15) * 32 + l4 * 8];
#pragma unroll
    for (int j = 0; j < 4; ++j)
      bh[j] = *(const short8v*)&lds[4096 + (wc * 64 + j * 16 + l15) * 32 + l4 * 8];
#pragma unroll
    for (int i = 0; i < 4; ++i)
#pragma unroll
      for (int j = 0; j < 4; ++j)
        acc[i][j] = __builtin_amdgcn_mfma_f32_16x16x32_bf16(ah[i], bh[j], acc[i][j], 0, 0, 0);
  }

  // epilogue: global col = col0 + wc*64 + j*16 + l15; block is entirely in one of q/k/v
  const int tt = colblk / 6;             // 0=q, 1=k, 2=v  (768/128 = 6 blocks per region)
  const int rcbase = (colblk % 6) * 128 + wc * 64;
#pragma unroll
  for (int i = 0; i < 4; ++i) {
    const int rowb = row0 + wr * 64 + i * 16 + l4 * 4;
#pragma unroll
    for (int j = 0; j < 4; ++j) {
      const int rc = rcbase + j * 16 + l15;
      const int h = rc >> 6, d = rc & 63;
#pragma unroll
      for (int r = 0; r < 4; ++r) {
        const int row = rowb + r;
        const int b = row >> 11, n = row & (Nn - 1);
        const size_t idx = ((size_t)(b * Hh + h) * Nn + n) * 64 + d;
        float val = acc[i][j][r];
        if (tt == 0) {
          float e = elu1(val);
          qp[idx] = e;
          qpb[idx] = f2bf(e);
        } else if (tt == 1) {
          float e = elu1(val);
          kp[idx] = e;
          kpb[idx] = f2bf(e);
        } else {
          vp[idx] = val;
        }
      }
    }
  }
}

// ---------------- MFMA GEMM (m97-style): C[z] = A[z][MxK] * BT[z][NxK]^T -------------
// TERMS=3: Ah*Bh + Ah*Bl + Al*Bh (fp32-grade).  TERMS=1: Ah*Bh only.
template <int TERMS, bool BIAS, bool DIV>
__global__ __launch_bounds__(BDIM) void mfma_gemm(
    const unsigned short* __restrict__ Ah, const unsigned short* __restrict__ Al,
    const unsigned short* __restrict__ BTh, const unsigned short* __restrict__ BTl,
    const float* __restrict__ bias, const float* __restrict__ denom,
    float* __restrict__ C, int M, int Nw, int K,
    long sAz, long sBz, long sCz) {
  constexpr int NMAT = (TERMS == 3) ? 4 : 2;
  __shared__ unsigned short lds[NMAT * 4096];  // per matrix: [128][32] ushort = 8 KB

  const int z = blockIdx.z;
  const unsigned short* A0 = Ah + (size_t)z * sAz;
  const unsigned short* B0 = BTh + (size_t)z * sBz;
  float* Cz = C + (size_t)z * sCz;

  const int tid = threadIdx.x;
  const int wave = tid >> 6, lane = tid & 63;
  const int wr = wave >> 1, wc = wave & 1;
  const int row0 = blockIdx.y * 128, col0 = blockIdx.x * 128;
  const int l15 = lane & 15, l4 = lane >> 4;

  const int srow = wave * 16 + (lane >> 2);
  const int scol = (lane & 3) * 8;
  const int wbase = wave * 512;

  f32x4 acc[4][4];
#pragma unroll
  for (int i = 0; i < 4; ++i)
#pragma unroll
    for (int j = 0; j < 4; ++j) acc[i][j] = {0.f, 0.f, 0.f, 0.f};

  for (int k0 = 0; k0 < K; k0 += 32) {
    __syncthreads();
    gll16(&A0[(size_t)(row0 + srow) * K + k0 + scol], lds + wbase);
    gll16(&A0[(size_t)(row0 + 64 + srow) * K + k0 + scol], lds + 2048 + wbase);
    gll16(&B0[(size_t)(col0 + srow) * K + k0 + scol], lds + 4096 + wbase);
    gll16(&B0[(size_t)(col0 + 64 + srow) * K + k0 + scol], lds + 4096 + 2048 + wbase);
    if constexpr (TERMS == 3) {
      const unsigned short* A1 = Al + (size_t)z * sAz;
      const unsigned short* B1 = BTl + (size_t)z * sBz;
      gll16(&A1[(size_t)(row0 + srow) * K + k0 + scol], lds + 8192 + wbase);
      gll16(&A1[(size_t)(row0 + 64 + srow) * K + k0 + scol], lds + 8192 + 2048 + wbase);
      gll16(&B1[(size_t)(col0 + srow) * K + k0 + scol], lds + 12288 + wbase);
      gll16(&B1[(size_t)(col0 + 64 + srow) * K + k0 + scol], lds + 12288 + 2048 + wbase);
    }
    __syncthreads();

    short8v ah[4], bh[4];
#pragma unroll
    for (int i = 0; i < 4; ++i)
      ah[i] = *(const short8v*)&lds[(wr * 64 + i * 16 + l15) * 32 + l4 * 8];
#pragma unroll
    for (int j = 0; j < 4; ++j)
      bh[j] = *(const short8v*)&lds[4096 + (wc * 64 + j * 16 + l15) * 32 + l4 * 8];
#pragma unroll
    for (int i = 0; i < 4; ++i)
#pragma unroll
      for (int j = 0; j < 4; ++j)
        acc[i][j] = __builtin_amdgcn_mfma_f32_16x16x32_bf16(ah[i], bh[j], acc[i][j], 0, 0, 0);
    if constexpr (TERMS == 3) {
      short8v al[4], bl[4];
#pragma unroll
      for (int i = 0; i < 4; ++i)
        al[i] = *(const short8v*)&lds[8192 + (wr * 64 + i * 16 + l15) * 32 + l4 * 8];
#pragma unroll
      for (int j = 0; j < 4; ++j)
        bl[j] = *(const short8v*)&lds[12288 + (wc * 64 + j * 16 + l15) * 32 + l4 * 8];
#pragma unroll
      for (int i = 0; i < 4; ++i)
#pragma unroll
        for (int j = 0; j < 4; ++j) {
          acc[i][j] = __builtin_amdgcn_mfma_f32_16x16x32_bf16(ah[i], bl[j], acc[i][j], 0, 0, 0);
          acc[i][j] = __builtin_amdgcn_mfma_f32_16x16x32_bf16(al[i], bh[j], acc[i][j], 0, 0, 0);
        }
    }
  }

  // epilogue: C/D layout col=lane&15, row=(lane>>4)*4+reg
#pragma unroll
  for (int i = 0; i < 4; ++i) {
    const int rbase = row0 + wr * 64 + i * 16 + l4 * 4;
    float rd[4];
    if (DIV) {
#pragma unroll
      for (int r = 0; r < 4; ++r) rd[r] = 1.0f / denom[(size_t)z * M + rbase + r];
    }
#pragma unroll
    for (int j = 0; j < 4; ++j) {
      const int col = col0 + wc * 64 + j * 16 + l15;
      float bs = BIAS ? bias[col] : 0.f;
#pragma unroll
      for (int r = 0; r < 4; ++r) {
        float o = acc[i][j][r];
        if (DIV) o *= rd[r];
        if (BIAS) o += bs;
        Cz[(size_t)(rbase + r) * Nw + col] = o;
      }
    }
  }
}

// ---------------- partial KV = k'^T v  and  Ksum = sum_n k' --------------------------
__global__ __launch_bounds__(BDIM) void kv_partial(const float* __restrict__ kp,
                                                   const float* __restrict__ vp,
                                                   float* __restrict__ kvpart,
                                                   float* __restrict__ kspart) {
  const int chunk = blockIdx.x, bh = blockIdx.y;
  __shared__ float ks[8][64];
  __shared__ float vs[8][64];
  const int tid = threadIdx.x;
  const int nn = tid >> 5, f2 = (tid & 31) << 1;
  const int e = tid & 63, dg = tid >> 6;
  float acc[16] = {};
  float ksacc = 0.f;
  const int n0base = chunk * CHROWS;
  for (int s = 0; s < CHROWS; s += 8) {
    int n = n0base + s + nn;
    float2 k2 = *(const float2*)&kp[(size_t)(bh * Nn + n) * 64 + f2];
    float2 v2 = *(const float2*)&vp[(size_t)(bh * Nn + n) * 64 + f2];
    __syncthreads();
    *(float2*)&ks[nn][f2] = k2;
    *(float2*)&vs[nn][f2] = v2;
    __syncthreads();
#pragma unroll
    for (int j = 0; j < 8; ++j) {
      float vv = vs[j][e];
#pragma unroll
      for (int d = 0; d < 16; ++d) acc[d] += ks[j][dg * 16 + d] * vv;
      if (tid < 64) ksacc += ks[j][tid];
    }
  }
  float* outp = kvpart + (size_t)(bh * NCHUNK + chunk) * 4096;
#pragma unroll
  for (int d = 0; d < 16; ++d) outp[(dg * 16 + d) * 64 + e] = acc[d];
  if (tid < 64) kspart[(bh * NCHUNK + chunk) * 64 + tid] = ksacc;
}

__global__ __launch_bounds__(BDIM) void kv_reduce(const float* __restrict__ kvpart,
                                                  const float* __restrict__ kspart,
                                                  float* __restrict__ kv,
                                                  float* __restrict__ ksum) {
  const int bh = blockIdx.x, tid = threadIdx.x;
#pragma unroll
  for (int i = 0; i < 16; ++i) {
    int idx = i * 256 + tid;
    float s = 0.f;
    for (int c = 0; c < NCHUNK; ++c) s += kvpart[(size_t)(bh * NCHUNK + c) * 4096 + idx];
    kv[(size_t)bh * 4096 + idx] = s;
  }
  if (tid < 64) {
    float s = 0.f;
    for (int c = 0; c < NCHUNK; ++c) s += kspart[(bh * NCHUNK + c) * 64 + tid];
    ksum[bh * 64 + tid] = s;
  }
}

// ---------------- denom[b,h,n] = q' . Ksum -------------------------------------------
__global__ __launch_bounds__(BDIM) void denom_kernel(const float* __restrict__ qp,
                                                     const float* __restrict__ ksum,
                                                     float* __restrict__ denom) {
  const int bh = blockIdx.y;
  const int n = blockIdx.x * BDIM + threadIdx.x;
  __shared__ float kss[64];
  if (threadIdx.x < 64) kss[threadIdx.x] = ksum[bh * 64 + threadIdx.x];
  __syncthreads();
  const float* qrow = qp + (size_t)(bh * Nn + n) * 64;
  float s = 0.f;
#pragma unroll
  for (int d4 = 0; d4 < 16; ++d4) {
    float4 q = *(const float4*)(qrow + d4 * 4);
    s += q.x * kss[d4 * 4] + q.y * kss[d4 * 4 + 1] + q.z * kss[d4 * 4 + 2] +
         q.w * kss[d4 * 4 + 3];
  }
  denom[bh * Nn + n] = s;
}

// ------ out_pre[b,n,h*64+c] = (q' . KV[:,c]) / denom, emitted as bf16 hi/lo ----------
__global__ __launch_bounds__(BDIM) void outpre_kernel(const float* __restrict__ qp,
                                                      const float* __restrict__ kv,
                                                      const float* __restrict__ denom,
                                                      unsigned short* __restrict__ oph,
                                                      unsigned short* __restrict__ opl) {
  const int nc = blockIdx.x, bh = blockIdx.y;
  const int b = bh / Hh, h = bh % Hh;
  __shared__ float KVs[4096];
  __shared__ float Qs2[4096];
  const int tid = threadIdx.x;
  const int n0 = nc * 64;
#pragma unroll
  for (int it = 0; it < 4; ++it) {
    int i = it * 1024 + tid * 4;
    *(float4*)&KVs[i] = *(const float4*)&kv[(size_t)bh * 4096 + i];
    *(float4*)&Qs2[i] = *(const float4*)&qp[(size_t)(bh * Nn + n0) * 64 + i];
  }
  __syncthreads();
  const int c = tid & 63, rg = tid >> 6;
  for (int j = 0; j < 16; ++j) {
    int r = rg * 16 + j;
    float s = 0.f;
#pragma unroll
    for (int d = 0; d < 64; ++d) s += Qs2[r * 64 + d] * KVs[d * 64 + c];
    int ng = n0 + r;
    float rd = 1.0f / denom[bh * Nn + ng];
    float o = s * rd;
    size_t idx = ((size_t)b * Nn + ng) * Cc + h * Dd + c;
    unsigned short hh = f2bf(o);
    oph[idx] = hh;
    opl[idx] = f2bf(o - bf2f(hh));
  }
}

extern "C" void kernel_launch(void* const* d_in, const int* in_sizes, int n_in,
                              void* d_out, int out_size, void* d_ws, size_t ws_size,
                              hipStream_t stream) {
  const float* x = (const float*)d_in[0];
  const float* w_qkv = (const float*)d_in[1];
  const float* w_proj = (const float*)d_in[2];
  const float* b_proj = (const float*)d_in[3];
  float* out = (float*)d_out;
  float* attn = out + (size_t)Bb * Nn * Cc;

  float* ws = (float*)d_ws;
  float* vp = ws;                            // 3145728
  float* qp = vp + 3145728;                  // 3145728
  float* kp = qp + 3145728;                  // 3145728
  float* kvpart = kp + 3145728;              // 1572864
  float* kspart = kvpart + 1572864;          // 24576
  float* kvm = kspart + 24576;               // 98304
  float* ksum = kvm + 98304;                 // 2048 (padded)
  float* denom = ksum + 2048;                // 49152
  unsigned short* us = (unsigned short*)(denom + 49152);
  unsigned short* xh = us;                   // 3145728
  unsigned short* wqh = xh + 3145728;        // 1769472
  unsigned short* wql = wqh + 1769472;       // 1769472 (written, unused)
  unsigned short* qpb = wql + 1769472;       // 3145728
  unsigned short* kpb = qpb + 3145728;       // 3145728
  unsigned short* oph = kpb + 3145728;       // 3145728
  unsigned short* opl = oph + 3145728;       // 3145728
  unsigned short* wph = opl + 3145728;       // 589824
  unsigned short* wpl = wph + 589824;        // 589824

  // qkv = x @ w_qkv, fused elu+1 + layout epilogue (1-term bf16 MFMA)
  cast_bf16<<<dim3(3072), BDIM, 0, stream>>>(x, xh);
  splitT<<<dim3(TC / 32, Cc / 32), BDIM, 0, stream>>>(w_qkv, wqh, wql, Cc, TC);
  gemm_qkv<<<dim3(TC / 128, 32), BDIM, 0, stream>>>(xh, wqh, qp, kp, vp, qpb, kpb);

  kv_partial<<<dim3(NCHUNK, BH), BDIM, 0, stream>>>(kp, vp, kvpart, kspart);
  kv_reduce<<<dim3(BH), BDIM, 0, stream>>>(kvpart, kspart, kvm, ksum);
  denom_kernel<<<dim3(Nn / BDIM, BH), BDIM, 0, stream>>>(qp, ksum, denom);

  // attn = (Q' K'^T) / denom  (single-term bf16 MFMA)
  mfma_gemm<1, false, true><<<dim3(Nn / 128, Nn / 128, BH), BDIM, 0, stream>>>(
      qpb, nullptr, kpb, nullptr, nullptr, denom, attn, Nn, Nn, Dd,
      (long)Nn * Dd, (long)Nn * Dd, (long)Nn * Nn);

  outpre_kernel<<<dim3(Nn / 64, BH), BDIM, 0, stream>>>(qp, kvm, denom, oph, opl);

  // out = outpre @ w_proj + b_proj  (split bf16 MFMA, fp32-grade)
  splitT<<<dim3(Cc / 32, Cc / 32), BDIM, 0, stream>>>(w_proj, wph, wpl, Cc, Cc);
  mfma_gemm<3, true, false><<<dim3(Cc / 128, 32, 1), BDIM, 0, stream>>>(
      oph, opl, wph, wpl, b_proj, nullptr, out, Bb * Nn, Cc, Cc, 0, 0, 0);
}

// Round 6
// 207.238 us; speedup vs baseline: 2.4563x; 1.0928x over previous
//
#include <hip/hip_runtime.h>
#include <hip/hip_bf16.h>
#include <cstdint>
#include <cmath>

#define BDIM 256

constexpr int Bb = 2;
constexpr int Nn = 2048;
constexpr int Cc = 768;
constexpr int Hh = 12;
constexpr int Dd = 64;
constexpr int TC = 3 * Cc;   // 2304
constexpr int BH = Bb * Hh;  // 24
constexpr int NCHUNK = 16;
constexpr int CHROWS = Nn / NCHUNK;  // 128

typedef __attribute__((ext_vector_type(8))) short short8v;   // 8 bf16 (4 VGPR)
typedef __attribute__((ext_vector_type(4))) float f32x4;

__device__ __forceinline__ float elu1(float x) {
  return x > 0.f ? x + 1.f : expf(x);
}

__device__ __forceinline__ unsigned short f2bf(float f) {
  uint32_t u = __float_as_uint(f);
  uint32_t r = (u + 0x7fff + ((u >> 16) & 1)) >> 16;
  return (unsigned short)r;
}
__device__ __forceinline__ float bf2f(unsigned short h) {
  return __uint_as_float(((uint32_t)h) << 16);
}

// async global->LDS, 16 B per lane; lds base must be wave-uniform (HW adds lane*16)
__device__ __forceinline__ void gll16(const unsigned short* g, unsigned short* ldsbase) {
  __builtin_amdgcn_global_load_lds((const __attribute__((address_space(1))) void*)g,
                                   (__attribute__((address_space(3))) void*)ldsbase,
                                   16, 0, 0);
}

// ---------------- fused input casts: x -> bf16; w_qkv^T, w_proj^T -> bf16 ------------
constexpr int XBLK = 3072;                       // x: 3.1M floats / 1024
constexpr int WQBLK = (TC / 32) * (Cc / 32);     // 72*24 = 1728
constexpr int WPBLK = (Cc / 32) * (Cc / 32);     // 24*24 = 576

__device__ __forceinline__ void castT_tile(const float* __restrict__ W,
                                           unsigned short* __restrict__ Wh,
                                           int K, int N, int n0, int k0, int tid,
                                           float (*t)[33]) {
  const int r = tid >> 3, c4 = (tid & 7) * 4;
  float4 v = *(const float4*)&W[(size_t)(k0 + r) * N + n0 + c4];
  t[r][c4 + 0] = v.x;
  t[r][c4 + 1] = v.y;
  t[r][c4 + 2] = v.z;
  t[r][c4 + 3] = v.w;
  __syncthreads();
  const int n = tid >> 3, k4 = (tid & 7) * 4;
  ushort4 h;
  h.x = f2bf(t[k4 + 0][n]);
  h.y = f2bf(t[k4 + 1][n]);
  h.z = f2bf(t[k4 + 2][n]);
  h.w = f2bf(t[k4 + 3][n]);
  *(ushort4*)&Wh[(size_t)(n0 + n) * K + k0 + k4] = h;
}

__global__ __launch_bounds__(BDIM) void fused_cast(const float* __restrict__ x,
                                                   const float* __restrict__ w_qkv,
                                                   const float* __restrict__ w_proj,
                                                   unsigned short* __restrict__ xh,
                                                   unsigned short* __restrict__ wqh,
                                                   unsigned short* __restrict__ wph) {
  __shared__ float t[32][33];
  const int bid = blockIdx.x, tid = threadIdx.x;
  if (bid < XBLK) {
    int i = (bid * BDIM + tid) * 4;
    float4 v = *(const float4*)&x[i];
    ushort4 h;
    h.x = f2bf(v.x);
    h.y = f2bf(v.y);
    h.z = f2bf(v.z);
    h.w = f2bf(v.w);
    *(ushort4*)&xh[i] = h;
  } else if (bid < XBLK + WQBLK) {
    int q = bid - XBLK;
    castT_tile(w_qkv, wqh, Cc, TC, (q % (TC / 32)) * 32, (q / (TC / 32)) * 32, tid, t);
  } else {
    int p = bid - XBLK - WQBLK;
    castT_tile(w_proj, wph, Cc, Cc, (p % (Cc / 32)) * 32, (p / (Cc / 32)) * 32, tid, t);
  }
}

// ---------------- fused qkv GEMM: [q|k|v] = x @ w_qkv with elu+1 epilogue ------------
__global__ __launch_bounds__(BDIM) void gemm_qkv(
    const unsigned short* __restrict__ A0, const unsigned short* __restrict__ B0,
    float* __restrict__ qp, float* __restrict__ kp, float* __restrict__ vp,
    unsigned short* __restrict__ qpb, unsigned short* __restrict__ kpb) {
  constexpr int K = Cc;  // 768
  __shared__ unsigned short lds[8192];  // A:[128][32], B:[128][32]

  const int tid = threadIdx.x;
  const int wave = tid >> 6, lane = tid & 63;
  const int wr = wave >> 1, wc = wave & 1;
  const int row0 = blockIdx.y * 128, colblk = blockIdx.x;
  const int col0 = colblk * 128;
  const int l15 = lane & 15, l4 = lane >> 4;

  const int srow = wave * 16 + (lane >> 2);
  const int scol = (lane & 3) * 8;
  const int wbase = wave * 512;

  f32x4 acc[4][4];
#pragma unroll
  for (int i = 0; i < 4; ++i)
#pragma unroll
    for (int j = 0; j < 4; ++j) acc[i][j] = {0.f, 0.f, 0.f, 0.f};

  for (int k0 = 0; k0 < K; k0 += 32) {
    __syncthreads();
    gll16(&A0[(size_t)(row0 + srow) * K + k0 + scol], lds + wbase);
    gll16(&A0[(size_t)(row0 + 64 + srow) * K + k0 + scol], lds + 2048 + wbase);
    gll16(&B0[(size_t)(col0 + srow) * K + k0 + scol], lds + 4096 + wbase);
    gll16(&B0[(size_t)(col0 + 64 + srow) * K + k0 + scol], lds + 4096 + 2048 + wbase);
    __syncthreads();

    short8v ah[4], bh[4];
#pragma unroll
    for (int i = 0; i < 4; ++i)
      ah[i] = *(const short8v*)&lds[(wr * 64 + i * 16 + l15) * 32 + l4 * 8];
#pragma unroll
    for (int j = 0; j < 4; ++j)
      bh[j] = *(const short8v*)&lds[4096 + (wc * 64 + j * 16 + l15) * 32 + l4 * 8];
#pragma unroll
    for (int i = 0; i < 4; ++i)
#pragma unroll
      for (int j = 0; j < 4; ++j)
        acc[i][j] = __builtin_amdgcn_mfma_f32_16x16x32_bf16(ah[i], bh[j], acc[i][j], 0, 0, 0);
  }

  // epilogue: block columns are entirely within one of q/k/v (768 = 6 blocks each)
  const int tt = colblk / 6;  // 0=q, 1=k, 2=v
  const int rcbase = (colblk % 6) * 128 + wc * 64;
#pragma unroll
  for (int i = 0; i < 4; ++i) {
    const int rowb = row0 + wr * 64 + i * 16 + l4 * 4;
#pragma unroll
    for (int j = 0; j < 4; ++j) {
      const int rc = rcbase + j * 16 + l15;
      const int h = rc >> 6, d = rc & 63;
#pragma unroll
      for (int r = 0; r < 4; ++r) {
        const int row = rowb + r;
        const int b = row >> 11, n = row & (Nn - 1);
        const size_t idx = ((size_t)(b * Hh + h) * Nn + n) * 64 + d;
        float val = acc[i][j][r];
        if (tt == 0) {
          float e = elu1(val);
          qp[idx] = e;
          qpb[idx] = f2bf(e);
        } else if (tt == 1) {
          float e = elu1(val);
          kp[idx] = e;
          kpb[idx] = f2bf(e);
        } else {
          vp[idx] = val;
        }
      }
    }
  }
}

// ---------------- MFMA GEMM (1-term bf16): C[z] = A[z][MxK] * BT[z][NxK]^T -----------
template <bool BIAS, bool DIV>
__global__ __launch_bounds__(BDIM) void mfma_gemm(
    const unsigned short* __restrict__ Ah, const unsigned short* __restrict__ BTh,
    const float* __restrict__ bias, const float* __restrict__ denom,
    float* __restrict__ C, int M, int Nw, int K,
    long sAz, long sBz, long sCz) {
  __shared__ unsigned short lds[8192];  // A:[128][32], B:[128][32]

  const int z = blockIdx.z;
  const unsigned short* A0 = Ah + (size_t)z * sAz;
  const unsigned short* B0 = BTh + (size_t)z * sBz;
  float* Cz = C + (size_t)z * sCz;

  const int tid = threadIdx.x;
  const int wave = tid >> 6, lane = tid & 63;
  const int wr = wave >> 1, wc = wave & 1;
  const int row0 = blockIdx.y * 128, col0 = blockIdx.x * 128;
  const int l15 = lane & 15, l4 = lane >> 4;

  const int srow = wave * 16 + (lane >> 2);
  const int scol = (lane & 3) * 8;
  const int wbase = wave * 512;

  f32x4 acc[4][4];
#pragma unroll
  for (int i = 0; i < 4; ++i)
#pragma unroll
    for (int j = 0; j < 4; ++j) acc[i][j] = {0.f, 0.f, 0.f, 0.f};

  for (int k0 = 0; k0 < K; k0 += 32) {
    __syncthreads();
    gll16(&A0[(size_t)(row0 + srow) * K + k0 + scol], lds + wbase);
    gll16(&A0[(size_t)(row0 + 64 + srow) * K + k0 + scol], lds + 2048 + wbase);
    gll16(&B0[(size_t)(col0 + srow) * K + k0 + scol], lds + 4096 + wbase);
    gll16(&B0[(size_t)(col0 + 64 + srow) * K + k0 + scol], lds + 4096 + 2048 + wbase);
    __syncthreads();

    short8v ah[4], bh[4];
#pragma unroll
    for (int i = 0; i < 4; ++i)
      ah[i] = *(const short8v*)&lds[(wr * 64 + i * 16 + l15) * 32 + l4 * 8];
#pragma unroll
    for (int j = 0; j < 4; ++j)
      bh[j] = *(const short8v*)&lds[4096 + (wc * 64 + j * 16 + l15) * 32 + l4 * 8];
#pragma unroll
    for (int i = 0; i < 4; ++i)
#pragma unroll
      for (int j = 0; j < 4; ++j)
        acc[i][j] = __builtin_amdgcn_mfma_f32_16x16x32_bf16(ah[i], bh[j], acc[i][j], 0, 0, 0);
  }

  // epilogue: C/D layout col=lane&15, row=(lane>>4)*4+reg
#pragma unroll
  for (int i = 0; i < 4; ++i) {
    const int rbase = row0 + wr * 64 + i * 16 + l4 * 4;
    float rd[4];
    if (DIV) {
#pragma unroll
      for (int r = 0; r < 4; ++r) rd[r] = 1.0f / denom[(size_t)z * M + rbase + r];
    }
#pragma unroll
    for (int j = 0; j < 4; ++j) {
      const int col = col0 + wc * 64 + j * 16 + l15;
      float bs = BIAS ? bias[col] : 0.f;
#pragma unroll
      for (int r = 0; r < 4; ++r) {
        float o = acc[i][j][r];
        if (DIV) o *= rd[r];
        if (BIAS) o += bs;
        Cz[(size_t)(rbase + r) * Nw + col] = o;
      }
    }
  }
}

// ---------------- partial KV = k'^T v  and  Ksum = sum_n k' --------------------------
__global__ __launch_bounds__(BDIM) void kv_partial(const float* __restrict__ kp,
                                                   const float* __restrict__ vp,
                                                   float* __restrict__ kvpart,
                                                   float* __restrict__ kspart) {
  const int chunk = blockIdx.x, bh = blockIdx.y;
  __shared__ float ks[8][64];
  __shared__ float vs[8][64];
  const int tid = threadIdx.x;
  const int nn = tid >> 5, f2 = (tid & 31) << 1;
  const int e = tid & 63, dg = tid >> 6;
  float acc[16] = {};
  float ksacc = 0.f;
  const int n0base = chunk * CHROWS;
  for (int s = 0; s < CHROWS; s += 8) {
    int n = n0base + s + nn;
    float2 k2 = *(const float2*)&kp[(size_t)(bh * Nn + n) * 64 + f2];
    float2 v2 = *(const float2*)&vp[(size_t)(bh * Nn + n) * 64 + f2];
    __syncthreads();
    *(float2*)&ks[nn][f2] = k2;
    *(float2*)&vs[nn][f2] = v2;
    __syncthreads();
#pragma unroll
    for (int j = 0; j < 8; ++j) {
      float vv = vs[j][e];
#pragma unroll
      for (int d = 0; d < 16; ++d) acc[d] += ks[j][dg * 16 + d] * vv;
      if (tid < 64) ksacc += ks[j][tid];
    }
  }
  float* outp = kvpart + (size_t)(bh * NCHUNK + chunk) * 4096;
#pragma unroll
  for (int d = 0; d < 16; ++d) outp[(dg * 16 + d) * 64 + e] = acc[d];
  if (tid < 64) kspart[(bh * NCHUNK + chunk) * 64 + tid] = ksacc;
}

// ---------------- wide reduce: grid (16, BH) -----------------------------------------
__global__ __launch_bounds__(BDIM) void kv_reduce(const float* __restrict__ kvpart,
                                                  const float* __restrict__ kspart,
                                                  float* __restrict__ kv,
                                                  float* __restrict__ ksum) {
  const int seg = blockIdx.x, bh = blockIdx.y, tid = threadIdx.x;
  const int idx = seg * 256 + tid;
  float s = 0.f;
#pragma unroll 4
  for (int c = 0; c < NCHUNK; ++c) s += kvpart[(size_t)(bh * NCHUNK + c) * 4096 + idx];
  kv[(size_t)bh * 4096 + idx] = s;
  if (tid < 4) {
    int e = seg * 4 + tid;
    float s2 = 0.f;
#pragma unroll 4
    for (int c = 0; c < NCHUNK; ++c) s2 += kspart[(bh * NCHUNK + c) * 64 + e];
    ksum[bh * 64 + e] = s2;
  }
}

// ------ fused: denom[b,h,n] = q'.Ksum ; out_pre = (q'.KV)/denom -> bf16 --------------
__global__ __launch_bounds__(BDIM) void outpre_kernel(const float* __restrict__ qp,
                                                      const float* __restrict__ kv,
                                                      const float* __restrict__ ksum,
                                                      float* __restrict__ denom,
                                                      unsigned short* __restrict__ oph) {
  const int nc = blockIdx.x, bh = blockIdx.y;
  const int b = bh / Hh, h = bh % Hh;
  __shared__ float KVs[4096];
  __shared__ float Qs2[4096];
  __shared__ float kss[64];
  __shared__ float dnv[64];
  const int tid = threadIdx.x;
  const int n0 = nc * 64;
  if (tid < 64) kss[tid] = ksum[bh * 64 + tid];
#pragma unroll
  for (int it = 0; it < 4; ++it) {
    int i = it * 1024 + tid * 4;
    *(float4*)&KVs[i] = *(const float4*)&kv[(size_t)bh * 4096 + i];
    *(float4*)&Qs2[i] = *(const float4*)&qp[(size_t)(bh * Nn + n0) * 64 + i];
  }
  __syncthreads();
  if (tid < 64) {
    const float* qrow = qp + (size_t)(bh * Nn + n0 + tid) * 64;
    float s = 0.f;
#pragma unroll
    for (int d4 = 0; d4 < 16; ++d4) {
      float4 q = *(const float4*)(qrow + d4 * 4);
      s += q.x * kss[d4 * 4] + q.y * kss[d4 * 4 + 1] + q.z * kss[d4 * 4 + 2] +
           q.w * kss[d4 * 4 + 3];
    }
    denom[bh * Nn + n0 + tid] = s;
    dnv[tid] = 1.0f / s;
  }
  __syncthreads();
  const int c = tid & 63, rg = tid >> 6;
  for (int j = 0; j < 16; ++j) {
    int r = rg * 16 + j;
    float s = 0.f;
#pragma unroll
    for (int d = 0; d < 64; ++d) s += Qs2[r * 64 + d] * KVs[d * 64 + c];
    int ng = n0 + r;
    size_t idx = ((size_t)b * Nn + ng) * Cc + h * Dd + c;
    oph[idx] = f2bf(s * dnv[r]);
  }
}

extern "C" void kernel_launch(void* const* d_in, const int* in_sizes, int n_in,
                              void* d_out, int out_size, void* d_ws, size_t ws_size,
                              hipStream_t stream) {
  const float* x = (const float*)d_in[0];
  const float* w_qkv = (const float*)d_in[1];
  const float* w_proj = (const float*)d_in[2];
  const float* b_proj = (const float*)d_in[3];
  float* out = (float*)d_out;
  float* attn = out + (size_t)Bb * Nn * Cc;

  float* ws = (float*)d_ws;
  float* vp = ws;                            // 3145728
  float* qp = vp + 3145728;                  // 3145728
  float* kp = qp + 3145728;                  // 3145728
  float* kvpart = kp + 3145728;              // 1572864
  float* kspart = kvpart + 1572864;          // 24576
  float* kvm = kspart + 24576;               // 98304
  float* ksum = kvm + 98304;                 // 2048 (padded)
  float* denom = ksum + 2048;                // 49152
  unsigned short* us = (unsigned short*)(denom + 49152);
  unsigned short* xh = us;                   // 3145728
  unsigned short* wqh = xh + 3145728;        // 1769472
  unsigned short* qpb = wqh + 1769472;       // 3145728
  unsigned short* kpb = qpb + 3145728;       // 3145728
  unsigned short* oph = kpb + 3145728;       // 3145728
  unsigned short* wph = oph + 3145728;       // 589824

  // 1. all input casts (x -> bf16, w_qkv^T -> bf16, w_proj^T -> bf16)
  fused_cast<<<dim3(XBLK + WQBLK + WPBLK), BDIM, 0, stream>>>(x, w_qkv, w_proj, xh, wqh,
                                                              wph);
  // 2. qkv = x @ w_qkv, fused elu+1 + [B,H,N,D] layout epilogue
  gemm_qkv<<<dim3(TC / 128, 32), BDIM, 0, stream>>>(xh, wqh, qp, kp, vp, qpb, kpb);
  // 3-4. KV = k'^T v, ksum = sum k'
  kv_partial<<<dim3(NCHUNK, BH), BDIM, 0, stream>>>(kp, vp, kvpart, kspart);
  kv_reduce<<<dim3(16, BH), BDIM, 0, stream>>>(kvpart, kspart, kvm, ksum);
  // 5. denom + out_pre (bf16)
  outpre_kernel<<<dim3(Nn / 64, BH), BDIM, 0, stream>>>(qp, kvm, ksum, denom, oph);
  // 6. attn = (Q' K'^T) / denom
  mfma_gemm<false, true><<<dim3(Nn / 128, Nn / 128, BH), BDIM, 0, stream>>>(
      qpb, kpb, nullptr, denom, attn, Nn, Nn, Dd,
      (long)Nn * Dd, (long)Nn * Dd, (long)Nn * Nn);
  // 7. out = outpre @ w_proj + b_proj
  mfma_gemm<true, false><<<dim3(Cc / 128, 32, 1), BDIM, 0, stream>>>(
      oph, wph, b_proj, nullptr, out, Bb * Nn, Cc, Cc, 0, 0, 0);
}

// Round 7
// 183.961 us; speedup vs baseline: 2.7671x; 1.1265x over previous
//
#include <hip/hip_runtime.h>
#include <hip/hip_bf16.h>
#include <cstdint>
#include <cmath>

#define BDIM 256

constexpr int Bb = 2;
constexpr int Nn = 2048;
constexpr int Cc = 768;
constexpr int Hh = 12;
constexpr int Dd = 64;
constexpr int TC = 3 * Cc;   // 2304
constexpr int BH = Bb * Hh;  // 24
constexpr int NCHUNK = 16;
constexpr int CHROWS = Nn / NCHUNK;  // 128

typedef __attribute__((ext_vector_type(8))) short short8v;   // 8 bf16 (4 VGPR)
typedef __attribute__((ext_vector_type(4))) float f32x4;

__device__ __forceinline__ float elu1(float x) {
  return x > 0.f ? x + 1.f : expf(x);
}

__device__ __forceinline__ unsigned short f2bf(float f) {
  uint32_t u = __float_as_uint(f);
  uint32_t r = (u + 0x7fff + ((u >> 16) & 1)) >> 16;
  return (unsigned short)r;
}
__device__ __forceinline__ float bf2f(unsigned short h) {
  return __uint_as_float(((uint32_t)h) << 16);
}

// async global->LDS, 16 B per lane; lds base must be wave-uniform (HW adds lane*16)
__device__ __forceinline__ void gll16(const unsigned short* g, unsigned short* ldsbase) {
  __builtin_amdgcn_global_load_lds((const __attribute__((address_space(1))) void*)g,
                                   (__attribute__((address_space(3))) void*)ldsbase,
                                   16, 0, 0);
}

// ---------------- fused input casts: x -> bf16; w_qkv^T, w_proj^T -> bf16 ------------
constexpr int XBLK = 3072;                       // x: 3.1M floats / 1024
constexpr int WQBLK = (TC / 32) * (Cc / 32);     // 72*24 = 1728
constexpr int WPBLK = (Cc / 32) * (Cc / 32);     // 24*24 = 576

__device__ __forceinline__ void castT_tile(const float* __restrict__ W,
                                           unsigned short* __restrict__ Wh,
                                           int K, int N, int n0, int k0, int tid,
                                           float (*t)[33]) {
  const int r = tid >> 3, c4 = (tid & 7) * 4;
  float4 v = *(const float4*)&W[(size_t)(k0 + r) * N + n0 + c4];
  t[r][c4 + 0] = v.x;
  t[r][c4 + 1] = v.y;
  t[r][c4 + 2] = v.z;
  t[r][c4 + 3] = v.w;
  __syncthreads();
  const int n = tid >> 3, k4 = (tid & 7) * 4;
  ushort4 h;
  h.x = f2bf(t[k4 + 0][n]);
  h.y = f2bf(t[k4 + 1][n]);
  h.z = f2bf(t[k4 + 2][n]);
  h.w = f2bf(t[k4 + 3][n]);
  *(ushort4*)&Wh[(size_t)(n0 + n) * K + k0 + k4] = h;
}

__global__ __launch_bounds__(BDIM) void fused_cast(const float* __restrict__ x,
                                                   const float* __restrict__ w_qkv,
                                                   const float* __restrict__ w_proj,
                                                   unsigned short* __restrict__ xh,
                                                   unsigned short* __restrict__ wqh,
                                                   unsigned short* __restrict__ wph) {
  __shared__ float t[32][33];
  const int bid = blockIdx.x, tid = threadIdx.x;
  if (bid < XBLK) {
    int i = (bid * BDIM + tid) * 4;
    float4 v = *(const float4*)&x[i];
    ushort4 h;
    h.x = f2bf(v.x);
    h.y = f2bf(v.y);
    h.z = f2bf(v.z);
    h.w = f2bf(v.w);
    *(ushort4*)&xh[i] = h;
  } else if (bid < XBLK + WQBLK) {
    int q = bid - XBLK;
    castT_tile(w_qkv, wqh, Cc, TC, (q % (TC / 32)) * 32, (q / (TC / 32)) * 32, tid, t);
  } else {
    int p = bid - XBLK - WQBLK;
    castT_tile(w_proj, wph, Cc, Cc, (p % (Cc / 32)) * 32, (p / (Cc / 32)) * 32, tid, t);
  }
}

// ---------------- unified 2-phase MFMA GEMM: C[z] = A[z][MxK] * BT[z][NxK]^T ---------
// EP=0: plain + bias (proj).  EP=1: /denom + LDS-transposed float4 stores (attn).
// EP=2: qkv epilogue (elu+1, [B,H,N,D] scatter to qp/kp/vp/qpb/kpb).
template <int EP>
__global__ __launch_bounds__(BDIM) void mfma_k(
    const unsigned short* __restrict__ A, const unsigned short* __restrict__ Bt,
    const float* __restrict__ bias, const float* __restrict__ denom,
    float* __restrict__ C, int Mrows, int Nw, int K,
    long sAz, long sBz, long sCz,
    float* __restrict__ qp, float* __restrict__ kp, float* __restrict__ vp,
    unsigned short* __restrict__ qpb, unsigned short* __restrict__ kpb) {
  __shared__ __align__(16) unsigned short lds[16384];  // 2 bufs x (A 8KB + B 8KB)
  __shared__ float dnls[128];

  const int z = blockIdx.z;
  const unsigned short* A0 = A + (size_t)z * sAz;
  const unsigned short* B0 = Bt + (size_t)z * sBz;
  float* Cz = C + (size_t)z * sCz;

  const int tid = threadIdx.x;
  const int wave = tid >> 6, lane = tid & 63;
  const int wr = wave >> 1, wc = wave & 1;
  const int row0 = blockIdx.y * 128, col0 = blockIdx.x * 128;
  const int l15 = lane & 15, l4 = lane >> 4;
  const int srow = wave * 16 + (lane >> 2);
  const int scol = (lane & 3) * 8;
  const int wbase = wave * 512;

  // EP1: issue denom load FIRST so it is the oldest in the vmcnt queue
  float dnv_reg = 0.f;
  if constexpr (EP == 1) dnv_reg = denom[(size_t)z * Mrows + row0 + (tid & 127)];

  auto STAGE = [&](int buf, int k0) {
    unsigned short* dst = lds + buf * 8192 + wbase;
    gll16(&A0[(size_t)(row0 + srow) * K + k0 + scol], dst);
    gll16(&A0[(size_t)(row0 + 64 + srow) * K + k0 + scol], dst + 2048);
    gll16(&B0[(size_t)(col0 + srow) * K + k0 + scol], dst + 4096);
    gll16(&B0[(size_t)(col0 + 64 + srow) * K + k0 + scol], dst + 6144);
  };

  f32x4 acc[4][4];
#pragma unroll
  for (int i = 0; i < 4; ++i)
#pragma unroll
    for (int j = 0; j < 4; ++j) acc[i][j] = {0.f, 0.f, 0.f, 0.f};

  auto COMPUTE = [&](int buf) {
    const unsigned short* la = lds + buf * 8192;
    const unsigned short* lb = la + 4096;
    short8v av[4], bv[4];
#pragma unroll
    for (int i = 0; i < 4; ++i)
      av[i] = *(const short8v*)&la[(wr * 64 + i * 16 + l15) * 32 + l4 * 8];
#pragma unroll
    for (int j = 0; j < 4; ++j)
      bv[j] = *(const short8v*)&lb[(wc * 64 + j * 16 + l15) * 32 + l4 * 8];
#pragma unroll
    for (int i = 0; i < 4; ++i)
#pragma unroll
      for (int j = 0; j < 4; ++j)
        acc[i][j] = __builtin_amdgcn_mfma_f32_16x16x32_bf16(av[i], bv[j], acc[i][j], 0, 0, 0);
  };

  const int nt = K >> 5;
  STAGE(0, 0);
  if (nt > 1) STAGE(1, 32);
  int cur = 0;
  for (int t = 0; t < nt; ++t) {
    if (t < nt - 1)
      asm volatile("s_waitcnt vmcnt(4)" ::: "memory");
    else
      asm volatile("s_waitcnt vmcnt(0)" ::: "memory");
    __builtin_amdgcn_s_barrier();
    COMPUTE(cur);
    if (t < nt - 2) {
      __builtin_amdgcn_s_barrier();
      STAGE(cur, (t + 2) * 32);
    }
    cur ^= 1;
  }

  if constexpr (EP == 0) {
    // plain + bias epilogue
#pragma unroll
    for (int i = 0; i < 4; ++i) {
      const int rbase = row0 + wr * 64 + i * 16 + l4 * 4;
#pragma unroll
      for (int j = 0; j < 4; ++j) {
        const int col = col0 + wc * 64 + j * 16 + l15;
        float bs = bias[col];
#pragma unroll
        for (int r = 0; r < 4; ++r)
          Cz[(size_t)(rbase + r) * Nw + col] = acc[i][j][r] + bs;
      }
    }
  } else if constexpr (EP == 1) {
    // /denom + LDS-transpose -> coalesced float4 stores
    if (tid < 128) dnls[tid] = 1.0f / dnv_reg;
    float* fl = (float*)lds;  // 32 rows x 132 floats (padded) = 16.9 KB
#pragma unroll
    for (int i = 0; i < 4; ++i) {
      __syncthreads();
#pragma unroll
      for (int j = 0; j < 4; ++j)
#pragma unroll
        for (int r = 0; r < 4; ++r)
          fl[(wr * 16 + l4 * 4 + r) * 132 + wc * 64 + j * 16 + l15] =
              acc[i][j][r] * dnls[wr * 64 + i * 16 + l4 * 4 + r];
      __syncthreads();
#pragma unroll
      for (int p = 0; p < 4; ++p) {
        int f4 = p * 256 + tid;
        int cr = f4 >> 5, c4 = (f4 & 31) * 4;
        float4 v = *(float4*)&fl[cr * 132 + c4];
        int grow = row0 + (cr >> 4) * 64 + i * 16 + (cr & 15);
        *(float4*)&Cz[(size_t)grow * Nw + col0 + c4] = v;
      }
    }
  } else {
    // qkv epilogue: elu+1 and [B,H,N,D] scatter (block cols within one of q/k/v)
    const int colblk = blockIdx.x;
    const int tt = colblk / 6;  // 0=q, 1=k, 2=v
    const int rcbase = (colblk % 6) * 128 + wc * 64;
#pragma unroll
    for (int i = 0; i < 4; ++i) {
      const int rowb = row0 + wr * 64 + i * 16 + l4 * 4;
#pragma unroll
      for (int j = 0; j < 4; ++j) {
        const int rc = rcbase + j * 16 + l15;
        const int h = rc >> 6, d = rc & 63;
#pragma unroll
        for (int r = 0; r < 4; ++r) {
          const int row = rowb + r;
          const int b = row >> 11, n = row & (Nn - 1);
          const size_t idx = ((size_t)(b * Hh + h) * Nn + n) * 64 + d;
          float val = acc[i][j][r];
          if (tt == 0) {
            float e = elu1(val);
            qp[idx] = e;
            qpb[idx] = f2bf(e);
          } else if (tt == 1) {
            float e = elu1(val);
            kp[idx] = e;
            kpb[idx] = f2bf(e);
          } else {
            vp[idx] = val;
          }
        }
      }
    }
  }
}

// ---------------- partial KV = k'^T v  and  Ksum = sum_n k' --------------------------
__global__ __launch_bounds__(BDIM) void kv_partial(const float* __restrict__ kp,
                                                   const float* __restrict__ vp,
                                                   float* __restrict__ kvpart,
                                                   float* __restrict__ kspart) {
  const int chunk = blockIdx.x, bh = blockIdx.y;
  __shared__ float ks[8][64];
  __shared__ float vs[8][64];
  const int tid = threadIdx.x;
  const int nn = tid >> 5, f2 = (tid & 31) << 1;
  const int e = tid & 63, dg = tid >> 6;
  float acc[16] = {};
  float ksacc = 0.f;
  const int n0base = chunk * CHROWS;
  for (int s = 0; s < CHROWS; s += 8) {
    int n = n0base + s + nn;
    float2 k2 = *(const float2*)&kp[(size_t)(bh * Nn + n) * 64 + f2];
    float2 v2 = *(const float2*)&vp[(size_t)(bh * Nn + n) * 64 + f2];
    __syncthreads();
    *(float2*)&ks[nn][f2] = k2;
    *(float2*)&vs[nn][f2] = v2;
    __syncthreads();
#pragma unroll
    for (int j = 0; j < 8; ++j) {
      float vv = vs[j][e];
#pragma unroll
      for (int d = 0; d < 16; ++d) acc[d] += ks[j][dg * 16 + d] * vv;
      if (tid < 64) ksacc += ks[j][tid];
    }
  }
  float* outp = kvpart + (size_t)(bh * NCHUNK + chunk) * 4096;
#pragma unroll
  for (int d = 0; d < 16; ++d) outp[(dg * 16 + d) * 64 + e] = acc[d];
  if (tid < 64) kspart[(bh * NCHUNK + chunk) * 64 + tid] = ksacc;
}

// ---------------- wide reduce: grid (16, BH) -----------------------------------------
__global__ __launch_bounds__(BDIM) void kv_reduce(const float* __restrict__ kvpart,
                                                  const float* __restrict__ kspart,
                                                  float* __restrict__ kv,
                                                  float* __restrict__ ksum) {
  const int seg = blockIdx.x, bh = blockIdx.y, tid = threadIdx.x;
  const int idx = seg * 256 + tid;
  float s = 0.f;
#pragma unroll 4
  for (int c = 0; c < NCHUNK; ++c) s += kvpart[(size_t)(bh * NCHUNK + c) * 4096 + idx];
  kv[(size_t)bh * 4096 + idx] = s;
  if (tid < 4) {
    int e = seg * 4 + tid;
    float s2 = 0.f;
#pragma unroll 4
    for (int c = 0; c < NCHUNK; ++c) s2 += kspart[(bh * NCHUNK + c) * 64 + e];
    ksum[bh * 64 + e] = s2;
  }
}

// ------ fused: denom[b,h,n] = q'.Ksum ; out_pre = (q'.KV)/denom -> bf16 --------------
__global__ __launch_bounds__(BDIM) void outpre_kernel(const float* __restrict__ qp,
                                                      const float* __restrict__ kv,
                                                      const float* __restrict__ ksum,
                                                      float* __restrict__ denom,
                                                      unsigned short* __restrict__ oph) {
  const int nc = blockIdx.x, bh = blockIdx.y;
  const int b = bh / Hh, h = bh % Hh;
  __shared__ float KVs[4096];
  __shared__ float Qs2[4096];
  __shared__ float kss[64];
  __shared__ float dnv[64];
  const int tid = threadIdx.x;
  const int n0 = nc * 64;
  if (tid < 64) kss[tid] = ksum[bh * 64 + tid];
#pragma unroll
  for (int it = 0; it < 4; ++it) {
    int i = it * 1024 + tid * 4;
    *(float4*)&KVs[i] = *(const float4*)&kv[(size_t)bh * 4096 + i];
    *(float4*)&Qs2[i] = *(const float4*)&qp[(size_t)(bh * Nn + n0) * 64 + i];
  }
  __syncthreads();
  if (tid < 64) {
    float s = 0.f;
#pragma unroll
    for (int d = 0; d < 64; ++d) s += Qs2[tid * 64 + d] * kss[d];
    denom[bh * Nn + n0 + tid] = s;
    dnv[tid] = 1.0f / s;
  }
  __syncthreads();
  const int c = tid & 63, rg = tid >> 6;
  for (int j = 0; j < 16; ++j) {
    int r = rg * 16 + j;
    float s = 0.f;
#pragma unroll
    for (int d = 0; d < 64; ++d) s += Qs2[r * 64 + d] * KVs[d * 64 + c];
    int ng = n0 + r;
    size_t idx = ((size_t)b * Nn + ng) * Cc + h * Dd + c;
    oph[idx] = f2bf(s * dnv[r]);
  }
}

extern "C" void kernel_launch(void* const* d_in, const int* in_sizes, int n_in,
                              void* d_out, int out_size, void* d_ws, size_t ws_size,
                              hipStream_t stream) {
  const float* x = (const float*)d_in[0];
  const float* w_qkv = (const float*)d_in[1];
  const float* w_proj = (const float*)d_in[2];
  const float* b_proj = (const float*)d_in[3];
  float* out = (float*)d_out;
  float* attn = out + (size_t)Bb * Nn * Cc;

  float* ws = (float*)d_ws;
  float* vp = ws;                            // 3145728
  float* qp = vp + 3145728;                  // 3145728
  float* kp = qp + 3145728;                  // 3145728
  float* kvpart = kp + 3145728;              // 1572864
  float* kspart = kvpart + 1572864;          // 24576
  float* kvm = kspart + 24576;               // 98304
  float* ksum = kvm + 98304;                 // 2048 (padded)
  float* denom = ksum + 2048;                // 49152
  unsigned short* us = (unsigned short*)(denom + 49152);
  unsigned short* xh = us;                   // 3145728
  unsigned short* wqh = xh + 3145728;        // 1769472
  unsigned short* qpb = wqh + 1769472;       // 3145728
  unsigned short* kpb = qpb + 3145728;       // 3145728
  unsigned short* oph = kpb + 3145728;       // 3145728
  unsigned short* wph = oph + 3145728;       // 589824

  // 1. all input casts (x -> bf16, w_qkv^T -> bf16, w_proj^T -> bf16)
  fused_cast<<<dim3(XBLK + WQBLK + WPBLK), BDIM, 0, stream>>>(x, w_qkv, w_proj, xh, wqh,
                                                              wph);
  // 2. qkv = x @ w_qkv, fused elu+1 + [B,H,N,D] layout epilogue
  mfma_k<2><<<dim3(TC / 128, 32, 1), BDIM, 0, stream>>>(
      xh, wqh, nullptr, nullptr, nullptr, Bb * Nn, TC, Cc, 0, 0, 0,
      qp, kp, vp, qpb, kpb);
  // 3-4. KV = k'^T v, ksum = sum k'
  kv_partial<<<dim3(NCHUNK, BH), BDIM, 0, stream>>>(kp, vp, kvpart, kspart);
  kv_reduce<<<dim3(16, BH), BDIM, 0, stream>>>(kvpart, kspart, kvm, ksum);
  // 5. denom + out_pre (bf16)
  outpre_kernel<<<dim3(Nn / 64, BH), BDIM, 0, stream>>>(qp, kvm, ksum, denom, oph);
  // 6. attn = (Q' K'^T) / denom
  mfma_k<1><<<dim3(Nn / 128, Nn / 128, BH), BDIM, 0, stream>>>(
      qpb, kpb, nullptr, denom, attn, Nn, Nn, Dd,
      (long)Nn * Dd, (long)Nn * Dd, (long)Nn * Nn,
      nullptr, nullptr, nullptr, nullptr, nullptr);
  // 7. out = outpre @ w_proj + b_proj
  mfma_k<0><<<dim3(Cc / 128, 32, 1), BDIM, 0, stream>>>(
      oph, wph, b_proj, nullptr, out, Bb * Nn, Cc, Cc, 0, 0, 0,
      nullptr, nullptr, nullptr, nullptr, nullptr);
}

// Round 8
// 171.280 us; speedup vs baseline: 2.9720x; 1.0740x over previous
//
#include <hip/hip_runtime.h>
#include <hip/hip_bf16.h>
#include <cstdint>
#include <cmath>

#define BDIM 256

constexpr int Bb = 2;
constexpr int Nn = 2048;
constexpr int Cc = 768;
constexpr int Hh = 12;
constexpr int Dd = 64;
constexpr int TC = 3 * Cc;   // 2304
constexpr int BH = Bb * Hh;  // 24
constexpr int NCHUNK = 16;
constexpr int CHROWS = Nn / NCHUNK;  // 128

typedef __attribute__((ext_vector_type(8))) short short8v;   // 8 bf16 (4 VGPR)
typedef __attribute__((ext_vector_type(4))) float f32x4;

__device__ __forceinline__ float elu1(float x) {
  return x > 0.f ? x + 1.f : expf(x);
}

__device__ __forceinline__ unsigned short f2bf(float f) {
  uint32_t u = __float_as_uint(f);
  uint32_t r = (u + 0x7fff + ((u >> 16) & 1)) >> 16;
  return (unsigned short)r;
}
__device__ __forceinline__ float bf2f(unsigned short h) {
  return __uint_as_float(((uint32_t)h) << 16);
}

// async global->LDS, 16 B per lane; lds base must be wave-uniform (HW adds lane*16)
__device__ __forceinline__ void gll16(const unsigned short* g, unsigned short* ldsbase) {
  __builtin_amdgcn_global_load_lds((const __attribute__((address_space(1))) void*)g,
                                   (__attribute__((address_space(3))) void*)ldsbase,
                                   16, 0, 0);
}

// ---------------- fused input casts: x -> bf16; w_qkv^T, w_proj^T -> bf16 ------------
constexpr int XBLK = 3072;
constexpr int WQBLK = (TC / 32) * (Cc / 32);     // 1728
constexpr int WPBLK = (Cc / 32) * (Cc / 32);     // 576

__device__ __forceinline__ void castT_tile(const float* __restrict__ W,
                                           unsigned short* __restrict__ Wh,
                                           int K, int N, int n0, int k0, int tid,
                                           float (*t)[33]) {
  const int r = tid >> 3, c4 = (tid & 7) * 4;
  float4 v = *(const float4*)&W[(size_t)(k0 + r) * N + n0 + c4];
  t[r][c4 + 0] = v.x;
  t[r][c4 + 1] = v.y;
  t[r][c4 + 2] = v.z;
  t[r][c4 + 3] = v.w;
  __syncthreads();
  const int n = tid >> 3, k4 = (tid & 7) * 4;
  ushort4 h;
  h.x = f2bf(t[k4 + 0][n]);
  h.y = f2bf(t[k4 + 1][n]);
  h.z = f2bf(t[k4 + 2][n]);
  h.w = f2bf(t[k4 + 3][n]);
  *(ushort4*)&Wh[(size_t)(n0 + n) * K + k0 + k4] = h;
}

__global__ __launch_bounds__(BDIM) void fused_cast(const float* __restrict__ x,
                                                   const float* __restrict__ w_qkv,
                                                   const float* __restrict__ w_proj,
                                                   unsigned short* __restrict__ xh,
                                                   unsigned short* __restrict__ wqh,
                                                   unsigned short* __restrict__ wph) {
  __shared__ float t[32][33];
  const int bid = blockIdx.x, tid = threadIdx.x;
  if (bid < XBLK) {
    int i = (bid * BDIM + tid) * 4;
    float4 v = *(const float4*)&x[i];
    ushort4 h;
    h.x = f2bf(v.x);
    h.y = f2bf(v.y);
    h.z = f2bf(v.z);
    h.w = f2bf(v.w);
    *(ushort4*)&xh[i] = h;
  } else if (bid < XBLK + WQBLK) {
    int q = bid - XBLK;
    castT_tile(w_qkv, wqh, Cc, TC, (q % (TC / 32)) * 32, (q / (TC / 32)) * 32, tid, t);
  } else {
    int p = bid - XBLK - WQBLK;
    castT_tile(w_proj, wph, Cc, Cc, (p % (Cc / 32)) * 32, (p / (Cc / 32)) * 32, tid, t);
  }
}

// ---------------- unified 2-phase MFMA GEMM: C[z] = A[z][MxK] * BT[z][NxK]^T ---------
// EP=0: plain + bias (proj).  EP=1: /denom + LDS-transposed float4 stores (attn).
// EP=2: qkv epilogue (elu+1, [B,H,N,D] scatter to kp/vp/qpb/kpb).
template <int EP>
__global__ __launch_bounds__(BDIM) void mfma_k(
    const unsigned short* __restrict__ A, const unsigned short* __restrict__ Bt,
    const float* __restrict__ bias, const float* __restrict__ denom,
    float* __restrict__ C, int Mrows, int Nw, int K,
    long sAz, long sBz, long sCz,
    float* __restrict__ kp, float* __restrict__ vp,
    unsigned short* __restrict__ qpb, unsigned short* __restrict__ kpb) {
  __shared__ __align__(16) unsigned short lds[16384];  // 2 bufs x (A 8KB + B 8KB)
  __shared__ float dnls[128];

  const int z = blockIdx.z;
  const unsigned short* A0 = A + (size_t)z * sAz;
  const unsigned short* B0 = Bt + (size_t)z * sBz;
  float* Cz = C + (size_t)z * sCz;

  const int tid = threadIdx.x;
  const int wave = tid >> 6, lane = tid & 63;
  const int wr = wave >> 1, wc = wave & 1;
  const int row0 = blockIdx.y * 128, col0 = blockIdx.x * 128;
  const int l15 = lane & 15, l4 = lane >> 4;
  const int srow = wave * 16 + (lane >> 2);
  const int scol = (lane & 3) * 8;
  const int wbase = wave * 512;

  // EP1: issue denom load FIRST so it is the oldest in the vmcnt queue
  float dnv_reg = 0.f;
  if constexpr (EP == 1) dnv_reg = denom[(size_t)z * Mrows + row0 + (tid & 127)];

  auto STAGE = [&](int buf, int k0) {
    unsigned short* dst = lds + buf * 8192 + wbase;
    gll16(&A0[(size_t)(row0 + srow) * K + k0 + scol], dst);
    gll16(&A0[(size_t)(row0 + 64 + srow) * K + k0 + scol], dst + 2048);
    gll16(&B0[(size_t)(col0 + srow) * K + k0 + scol], dst + 4096);
    gll16(&B0[(size_t)(col0 + 64 + srow) * K + k0 + scol], dst + 6144);
  };

  f32x4 acc[4][4];
#pragma unroll
  for (int i = 0; i < 4; ++i)
#pragma unroll
    for (int j = 0; j < 4; ++j) acc[i][j] = {0.f, 0.f, 0.f, 0.f};

  auto COMPUTE = [&](int buf) {
    const unsigned short* la = lds + buf * 8192;
    const unsigned short* lb = la + 4096;
    short8v av[4], bv[4];
#pragma unroll
    for (int i = 0; i < 4; ++i)
      av[i] = *(const short8v*)&la[(wr * 64 + i * 16 + l15) * 32 + l4 * 8];
#pragma unroll
    for (int j = 0; j < 4; ++j)
      bv[j] = *(const short8v*)&lb[(wc * 64 + j * 16 + l15) * 32 + l4 * 8];
#pragma unroll
    for (int i = 0; i < 4; ++i)
#pragma unroll
      for (int j = 0; j < 4; ++j)
        acc[i][j] = __builtin_amdgcn_mfma_f32_16x16x32_bf16(av[i], bv[j], acc[i][j], 0, 0, 0);
  };

  const int nt = K >> 5;
  STAGE(0, 0);
  if (nt > 1) STAGE(1, 32);
  int cur = 0;
  for (int t = 0; t < nt; ++t) {
    if (t < nt - 1)
      asm volatile("s_waitcnt vmcnt(4)" ::: "memory");
    else
      asm volatile("s_waitcnt vmcnt(0)" ::: "memory");
    __builtin_amdgcn_s_barrier();
    COMPUTE(cur);
    if (t < nt - 2) {
      __builtin_amdgcn_s_barrier();
      STAGE(cur, (t + 2) * 32);
    }
    cur ^= 1;
  }

  if constexpr (EP == 0) {
#pragma unroll
    for (int i = 0; i < 4; ++i) {
      const int rbase = row0 + wr * 64 + i * 16 + l4 * 4;
#pragma unroll
      for (int j = 0; j < 4; ++j) {
        const int col = col0 + wc * 64 + j * 16 + l15;
        float bs = bias[col];
#pragma unroll
        for (int r = 0; r < 4; ++r)
          Cz[(size_t)(rbase + r) * Nw + col] = acc[i][j][r] + bs;
      }
    }
  } else if constexpr (EP == 1) {
    if (tid < 128) dnls[tid] = 1.0f / dnv_reg;
    float* fl = (float*)lds;  // 32 rows x 132 floats (padded)
#pragma unroll
    for (int i = 0; i < 4; ++i) {
      __syncthreads();
#pragma unroll
      for (int j = 0; j < 4; ++j)
#pragma unroll
        for (int r = 0; r < 4; ++r)
          fl[(wr * 16 + l4 * 4 + r) * 132 + wc * 64 + j * 16 + l15] =
              acc[i][j][r] * dnls[wr * 64 + i * 16 + l4 * 4 + r];
      __syncthreads();
#pragma unroll
      for (int p = 0; p < 4; ++p) {
        int f4 = p * 256 + tid;
        int cr = f4 >> 5, c4 = (f4 & 31) * 4;
        float4 v = *(float4*)&fl[cr * 132 + c4];
        int grow = row0 + (cr >> 4) * 64 + i * 16 + (cr & 15);
        *(float4*)&Cz[(size_t)grow * Nw + col0 + c4] = v;
      }
    }
  } else {
    // qkv epilogue: elu+1 and [B,H,N,D] scatter (block cols within one of q/k/v)
    const int colblk = blockIdx.x;
    const int tt = colblk / 6;  // 0=q, 1=k, 2=v
    const int rcbase = (colblk % 6) * 128 + wc * 64;
#pragma unroll
    for (int i = 0; i < 4; ++i) {
      const int rowb = row0 + wr * 64 + i * 16 + l4 * 4;
#pragma unroll
      for (int j = 0; j < 4; ++j) {
        const int rc = rcbase + j * 16 + l15;
        const int h = rc >> 6, d = rc & 63;
#pragma unroll
        for (int r = 0; r < 4; ++r) {
          const int row = rowb + r;
          const int b = row >> 11, n = row & (Nn - 1);
          const size_t idx = ((size_t)(b * Hh + h) * Nn + n) * 64 + d;
          float val = acc[i][j][r];
          if (tt == 0) {
            qpb[idx] = f2bf(elu1(val));
          } else if (tt == 1) {
            float e = elu1(val);
            kp[idx] = e;
            kpb[idx] = f2bf(e);
          } else {
            vp[idx] = val;
          }
        }
      }
    }
  }
}

// ---------------- partial KV = k'^T v  and  Ksum = sum_n k' --------------------------
__global__ __launch_bounds__(BDIM) void kv_partial(const float* __restrict__ kp,
                                                   const float* __restrict__ vp,
                                                   float* __restrict__ kvpart,
                                                   float* __restrict__ kspart) {
  const int chunk = blockIdx.x, bh = blockIdx.y;
  __shared__ float ks[8][64];
  __shared__ float vs[8][64];
  const int tid = threadIdx.x;
  const int nn = tid >> 5, f2 = (tid & 31) << 1;
  const int e = tid & 63, dg = tid >> 6;
  float acc[16] = {};
  float ksacc = 0.f;
  const int n0base = chunk * CHROWS;
  for (int s = 0; s < CHROWS; s += 8) {
    int n = n0base + s + nn;
    float2 k2 = *(const float2*)&kp[(size_t)(bh * Nn + n) * 64 + f2];
    float2 v2 = *(const float2*)&vp[(size_t)(bh * Nn + n) * 64 + f2];
    __syncthreads();
    *(float2*)&ks[nn][f2] = k2;
    *(float2*)&vs[nn][f2] = v2;
    __syncthreads();
#pragma unroll
    for (int j = 0; j < 8; ++j) {
      float vv = vs[j][e];
#pragma unroll
      for (int d = 0; d < 16; ++d) acc[d] += ks[j][dg * 16 + d] * vv;
      if (tid < 64) ksacc += ks[j][tid];
    }
  }
  float* outp = kvpart + (size_t)(bh * NCHUNK + chunk) * 4096;
#pragma unroll
  for (int d = 0; d < 16; ++d) outp[(dg * 16 + d) * 64 + e] = acc[d];
  if (tid < 64) kspart[(bh * NCHUNK + chunk) * 64 + tid] = ksacc;
}

// -------- reduce: KV^T -> bf16 [dv][dk], ksum fp32; grid (16, BH) --------------------
__global__ __launch_bounds__(BDIM) void kv_reduce(const float* __restrict__ kvpart,
                                                  const float* __restrict__ kspart,
                                                  unsigned short* __restrict__ kvtb,
                                                  float* __restrict__ ksum) {
  const int seg = blockIdx.x, bh = blockIdx.y, tid = threadIdx.x;
  const int idx = seg * 256 + tid;
  float s = 0.f;
#pragma unroll 4
  for (int c = 0; c < NCHUNK; ++c) s += kvpart[(size_t)(bh * NCHUNK + c) * 4096 + idx];
  const int dk = idx >> 6, dv = idx & 63;
  kvtb[(size_t)bh * 4096 + dv * 64 + dk] = f2bf(s);  // transposed bf16
  if (tid < 4) {
    int e = seg * 4 + tid;
    float s2 = 0.f;
#pragma unroll 4
    for (int c = 0; c < NCHUNK; ++c) s2 += kspart[(bh * NCHUNK + c) * 64 + e];
    ksum[bh * 64 + e] = s2;
  }
}

// ------ fused MFMA outpre: denom = q'.ksum (from A-frags); oph = (q'.KV)/denom -------
// grid (Nn/128, BH); 4 waves x (32 rows x 64 cols), K=64. No LDS staging.
__global__ __launch_bounds__(BDIM) void outpre_mfma(
    const unsigned short* __restrict__ qpb, const unsigned short* __restrict__ kvtb,
    const float* __restrict__ ksum, float* __restrict__ denom,
    unsigned short* __restrict__ oph) {
  const int nc = blockIdx.x, bh = blockIdx.y;
  const int b = bh / Hh, h = bh % Hh;
  __shared__ float kss[64];
  __shared__ float dnls[128];
  const int tid = threadIdx.x;
  const int wv = tid >> 6, lane = tid & 63;
  const int l15 = lane & 15, l4 = lane >> 4;
  if (tid < 64) kss[tid] = ksum[bh * 64 + tid];

  const int rowb = nc * 128 + wv * 32;  // n base for this wave
  const unsigned short* Aq = qpb + ((size_t)bh * Nn + rowb) * 64;
  const unsigned short* Bk = kvtb + (size_t)bh * 4096;

  short8v av[2][2], bv[4][2];
#pragma unroll
  for (int ks = 0; ks < 2; ++ks) {
#pragma unroll
    for (int i = 0; i < 2; ++i)
      av[i][ks] = *(const short8v*)&Aq[(size_t)(i * 16 + l15) * 64 + ks * 32 + l4 * 8];
#pragma unroll
    for (int j = 0; j < 4; ++j)
      bv[j][ks] = *(const short8v*)&Bk[(size_t)(j * 16 + l15) * 64 + ks * 32 + l4 * 8];
  }
  f32x4 acc[2][4];
#pragma unroll
  for (int i = 0; i < 2; ++i)
#pragma unroll
    for (int j = 0; j < 4; ++j) acc[i][j] = {0.f, 0.f, 0.f, 0.f};
#pragma unroll
  for (int ks = 0; ks < 2; ++ks)
#pragma unroll
    for (int i = 0; i < 2; ++i)
#pragma unroll
      for (int j = 0; j < 4; ++j)
        acc[i][j] = __builtin_amdgcn_mfma_f32_16x16x32_bf16(av[i][ks], bv[j][ks],
                                                            acc[i][j], 0, 0, 0);

  __syncthreads();  // kss ready
  float dpart[2] = {0.f, 0.f};
#pragma unroll
  for (int ks = 0; ks < 2; ++ks)
#pragma unroll
    for (int i = 0; i < 2; ++i)
#pragma unroll
      for (int t = 0; t < 8; ++t)
        dpart[i] += bf2f((unsigned short)av[i][ks][t]) * kss[ks * 32 + l4 * 8 + t];
#pragma unroll
  for (int i = 0; i < 2; ++i) {
    dpart[i] += __shfl_xor(dpart[i], 16);
    dpart[i] += __shfl_xor(dpart[i], 32);
    if (l4 == 0) {
      dnls[wv * 32 + i * 16 + l15] = dpart[i];
      denom[(size_t)bh * Nn + rowb + i * 16 + l15] = dpart[i];
    }
  }
  __syncthreads();
#pragma unroll
  for (int i = 0; i < 2; ++i) {
#pragma unroll
    for (int r = 0; r < 4; ++r) {
      const int rl = i * 16 + l4 * 4 + r;  // C/D row within wave's 32
      const float rd = 1.0f / dnls[wv * 32 + rl];
      const int nrow = rowb + rl;
#pragma unroll
      for (int j = 0; j < 4; ++j)
        oph[((size_t)b * Nn + nrow) * Cc + h * 64 + j * 16 + l15] =
            f2bf(acc[i][j][r] * rd);
    }
  }
}

extern "C" void kernel_launch(void* const* d_in, const int* in_sizes, int n_in,
                              void* d_out, int out_size, void* d_ws, size_t ws_size,
                              hipStream_t stream) {
  const float* x = (const float*)d_in[0];
  const float* w_qkv = (const float*)d_in[1];
  const float* w_proj = (const float*)d_in[2];
  const float* b_proj = (const float*)d_in[3];
  float* out = (float*)d_out;
  float* attn = out + (size_t)Bb * Nn * Cc;

  float* ws = (float*)d_ws;
  float* vp = ws;                            // 3145728
  float* kp = vp + 3145728;                  // 3145728
  float* kvpart = kp + 3145728;              // 1572864
  float* kspart = kvpart + 1572864;          // 24576
  float* ksum = kspart + 24576;              // 2048 (padded)
  float* denom = ksum + 2048;                // 49152
  unsigned short* us = (unsigned short*)(denom + 49152);
  unsigned short* xh = us;                   // 3145728
  unsigned short* wqh = xh + 3145728;        // 1769472
  unsigned short* qpb = wqh + 1769472;       // 3145728
  unsigned short* kpb = qpb + 3145728;       // 3145728
  unsigned short* kvtb = kpb + 3145728;      // 98304
  unsigned short* oph = kvtb + 98304;        // 3145728
  unsigned short* wph = oph + 3145728;       // 589824

  // 1. input casts
  fused_cast<<<dim3(XBLK + WQBLK + WPBLK), BDIM, 0, stream>>>(x, w_qkv, w_proj, xh, wqh,
                                                              wph);
  // 2. qkv = x @ w_qkv, fused elu+1 + [B,H,N,D] layout epilogue
  mfma_k<2><<<dim3(TC / 128, 32, 1), BDIM, 0, stream>>>(
      xh, wqh, nullptr, nullptr, nullptr, Bb * Nn, TC, Cc, 0, 0, 0,
      kp, vp, qpb, kpb);
  // 3-4. KV = k'^T v (fp32), reduce -> KV^T bf16 + ksum
  kv_partial<<<dim3(NCHUNK, BH), BDIM, 0, stream>>>(kp, vp, kvpart, kspart);
  kv_reduce<<<dim3(16, BH), BDIM, 0, stream>>>(kvpart, kspart, kvtb, ksum);
  // 5. denom + out_pre via register MFMA
  outpre_mfma<<<dim3(Nn / 128, BH), BDIM, 0, stream>>>(qpb, kvtb, ksum, denom, oph);
  // 6. attn = (Q' K'^T) / denom
  mfma_k<1><<<dim3(Nn / 128, Nn / 128, BH), BDIM, 0, stream>>>(
      qpb, kpb, nullptr, denom, attn, Nn, Nn, Dd,
      (long)Nn * Dd, (long)Nn * Dd, (long)Nn * Nn,
      nullptr, nullptr, nullptr, nullptr);
  // 7. out = outpre @ w_proj + b_proj
  mfma_k<0><<<dim3(Cc / 128, 32, 1), BDIM, 0, stream>>>(
      oph, wph, b_proj, nullptr, out, Bb * Nn, Cc, Cc, 0, 0, 0,
      nullptr, nullptr, nullptr, nullptr);
}